// Round 11
// baseline (534.734 us; speedup 1.0000x reference)
//
#include <hip/hip_runtime.h>

#define NT 50000   // nodes
#define NE 800000  // edges per edge-type
#define NG 256     // graphs
#define DIM 128
#define GEMM_B ((NT + 127) / 128)    // 391 MFMA-GEMM blocks per encoder

// CSR-build partition constants
#define NB 128                        // coarse dst buckets
#define BW 391                        // bucket width: 128*391 = 50048 >= NT
#define PB 196                        // partition blocks
#define PCH 4096                      // edges per partition block
#define HCN (NB * PB)                 // 25088

typedef short s16x8 __attribute__((ext_vector_type(8)));
typedef float f32x16 __attribute__((ext_vector_type(16)));

__device__ __forceinline__ unsigned short f32_to_bf16(float f) {
    unsigned int u = __float_as_uint(f);
    u += 0x7FFFu + ((u >> 16) & 1u);   // round-to-nearest-even
    return (unsigned short)(u >> 16);
}
__device__ __forceinline__ float bf16_to_f32(unsigned short h) {
    return __uint_as_float(((unsigned int)h) << 16);
}

// ---------------------------------------------------------------------------
__global__ __launch_bounds__(256) void tobf16_kernel(const float* __restrict__ in,
                                                     unsigned short* __restrict__ out) {
    int i = blockIdx.x * 256 + threadIdx.x;
    if (i >= NT * 32) return;
    float4 v = ((const float4*)in)[i];
    ushort4 o;
    o.x = f32_to_bf16(v.x); o.y = f32_to_bf16(v.y);
    o.z = f32_to_bf16(v.z); o.w = f32_to_bf16(v.w);
    ((ushort4*)out)[i] = o;
}

// ---------------------------------------------------------------------------
// CSR build (both edge types at once, blockIdx.y = e), 2-level counting sort
// ---------------------------------------------------------------------------
__global__ __launch_bounds__(256) void csr_part_hist_kernel(
        const int* __restrict__ dstAll, int* __restrict__ hcoarseAll) {
    const int* dst = dstAll + (size_t)blockIdx.y * NE;
    int* hcoarse = hcoarseAll + (size_t)blockIdx.y * HCN;
    __shared__ int h[NB];
    if (threadIdx.x < NB) h[threadIdx.x] = 0;
    __syncthreads();
#pragma unroll
    for (int i = 0; i < PCH / 256; ++i) {
        int e = blockIdx.x * PCH + i * 256 + threadIdx.x;
        if (e < NE) atomicAdd(&h[dst[e] / BW], 1);
    }
    __syncthreads();
    if (threadIdx.x < NB)
        hcoarse[threadIdx.x * PB + blockIdx.x] = h[threadIdx.x];
}

__global__ __launch_bounds__(1024) void csr_scan_kernel(
        const int* __restrict__ hcoarseAll, int* __restrict__ offAll,
        int* __restrict__ bucketBaseAll, int* __restrict__ indptrAll) {
    const int* hcoarse = hcoarseAll + (size_t)blockIdx.x * HCN;
    int* off = offAll + (size_t)blockIdx.x * HCN;
    int* bucketBase = bucketBaseAll + (size_t)blockIdx.x * (NB + 1);
    int* indptr = indptrAll + (size_t)blockIdx.x * (NT + 1);
    __shared__ int ps[1024];
    int t = threadIdx.x;
    const int CH = (HCN + 1023) / 1024;  // 25
    int beg = t * CH, end = beg + CH; if (end > HCN) end = HCN;
    int s = 0;
    for (int i = beg; i < end; ++i) s += hcoarse[i];
    ps[t] = s;
    __syncthreads();
    for (int o = 1; o < 1024; o <<= 1) {
        int v = (t >= o) ? ps[t - o] : 0;
        __syncthreads();
        ps[t] += v;
        __syncthreads();
    }
    int run = (t == 0) ? 0 : ps[t - 1];
    for (int i = beg; i < end; ++i) {
        off[i] = run;
        if (i % PB == 0) bucketBase[i / PB] = run;
        run += hcoarse[i];
    }
    if (t == 1023) bucketBase[NB] = NE;
    if (t == 0) indptr[NT] = NE;
}

__global__ __launch_bounds__(256) void csr_scatter_kernel(
        const int* __restrict__ srcAll, const int* __restrict__ dstAll,
        const int* __restrict__ offAll, unsigned int* __restrict__ partAll) {
    const int* src = srcAll + (size_t)blockIdx.y * NE;
    const int* dst = dstAll + (size_t)blockIdx.y * NE;
    const int* off = offAll + (size_t)blockIdx.y * HCN;
    unsigned int* part = partAll + (size_t)blockIdx.y * NE;
    __shared__ int cur[NB];
    if (threadIdx.x < NB) cur[threadIdx.x] = off[threadIdx.x * PB + blockIdx.x];
    __syncthreads();
#pragma unroll
    for (int i = 0; i < PCH / 256; ++i) {
        int e = blockIdx.x * PCH + i * 256 + threadIdx.x;
        if (e < NE) {
            int d = dst[e];
            int b = d / BW;
            int pos = atomicAdd(&cur[b], 1);
            part[pos] = ((unsigned int)(d - b * BW) << 16) | (unsigned int)src[e];
        }
    }
}

__global__ __launch_bounds__(256) void csr_finalize_kernel(
        const unsigned int* __restrict__ partAll,
        const int* __restrict__ bucketBaseAll,
        int* __restrict__ indptrAll, int* __restrict__ esrcAll) {
    const unsigned int* part = partAll + (size_t)blockIdx.y * NE;
    const int* bucketBase = bucketBaseAll + (size_t)blockIdx.y * (NB + 1);
    int* indptr = indptrAll + (size_t)blockIdx.y * (NT + 1);
    int* esrc = esrcAll + (size_t)blockIdx.y * NE;
    __shared__ int cnt[512];
    __shared__ int excl[512];
    __shared__ int ps[256];
    __shared__ int cur[BW + 1];
    int b = blockIdx.x, t = threadIdx.x;
    int base = bucketBase[b];
    int n = bucketBase[b + 1] - base;
    cnt[t] = 0; cnt[t + 256] = 0;
    for (int j = t; j <= BW; j += 256) cur[j] = 0;
    __syncthreads();
    for (int i = t; i < n; i += 256) atomicAdd(&cnt[part[base + i] >> 16], 1);
    __syncthreads();
    int a0 = cnt[2 * t], a1 = cnt[2 * t + 1];
    ps[t] = a0 + a1;
    __syncthreads();
    for (int o = 1; o < 256; o <<= 1) {
        int v = (t >= o) ? ps[t - o] : 0;
        __syncthreads();
        ps[t] += v;
        __syncthreads();
    }
    int before = (t == 0) ? 0 : ps[t - 1];
    excl[2 * t] = before;
    excl[2 * t + 1] = before + a0;
    __syncthreads();
    int node0 = b * BW;
    for (int j = t; j < BW; j += 256) {
        int gn = node0 + j;
        if (gn < NT) indptr[gn] = base + excl[j];
    }
    for (int i = t; i < n; i += 256) {
        unsigned int pk = part[base + i];
        int dl = pk >> 16;
        int pos = atomicAdd(&cur[dl], 1);
        esrc[base + excl[dl] + pos] = (int)(pk & 0xFFFFu);
    }
}

// ---------------------------------------------------------------------------
// Aggregation + bf16 hi/lo split. One node per wave; half-wave hw owns edges
// [j+8hw, j+8hw+8) of each 16-edge chunk. Full chunks run UNMASKED (plain
// adds); a single masked 8-deep chunk covers the <=16-edge tail — depth stays
// 8 for every node (R9 lesson) while full chunks shed the cndmask/fmaf-mask
// VALU overhead (R10: VALUBusy 60%). __shfl_xor(32) combines halves.
// ---------------------------------------------------------------------------
__global__ __launch_bounds__(256) void agg_split_kernel(
        const float* __restrict__ h, long hStride,
        const unsigned short* __restrict__ hb, long hbStride,
        const int* __restrict__ indptr2, const int* __restrict__ esrc2,
        const float* __restrict__ eps_p, int l,
        unsigned short* __restrict__ xout2) {
    int e = blockIdx.y;
    const float* hs = h + (size_t)e * hStride;
    const unsigned short* hbs = hb + (size_t)e * hbStride;
    const int* indptr = indptr2 + (size_t)e * (NT + 1);
    const int* esrc = esrc2 + (size_t)e * NE;
    unsigned short* xo = xout2 + (size_t)e * NT * 256;
    int node = blockIdx.x * 4 + (threadIdx.x >> 6);   // 1 node per wave
    if (node >= NT) return;
    int lane = threadIdx.x & 63;
    int half = lane >> 5, c = lane & 31;
    float s0 = 0.f, s1 = 0.f, s2 = 0.f, s3 = 0.f;
    if (half == 0) {
        float e1 = 1.0f + eps_p[e * 2 + l];
        float4 a = ((const float4*)hs)[(size_t)node * 32 + c];
        s0 = e1 * a.x; s1 = e1 * a.y; s2 = e1 * a.z; s3 = e1 * a.w;
    }
    int beg = indptr[node], end = indptr[node + 1];
    int deg = end - beg;
    int endFull = beg + (deg & ~15);
    int j = beg;
    for (; j < endFull; j += 16) {              // unmasked full chunks
        int b0 = j + half * 8;
        int idx[8];
#pragma unroll
        for (int k = 0; k < 8; ++k) idx[k] = esrc[b0 + k];
        ushort4 v[8];
#pragma unroll
        for (int k = 0; k < 8; ++k)
            v[k] = *(const ushort4*)(hbs + (size_t)idx[k] * 128 + c * 4);
#pragma unroll
        for (int k = 0; k < 8; ++k) {
            s0 += bf16_to_f32(v[k].x);
            s1 += bf16_to_f32(v[k].y);
            s2 += bf16_to_f32(v[k].z);
            s3 += bf16_to_f32(v[k].w);
        }
    }
    if (j < end) {                              // one masked 8-deep tail chunk
        int b0 = j + half * 8;
        int idx[8];
        float m[8];
#pragma unroll
        for (int k = 0; k < 8; ++k) {
            int jj = b0 + k;
            int ok = jj < end;
            idx[k] = esrc[ok ? jj : end - 1];   // clamp valid (deg > 0 here)
            m[k] = ok ? 1.f : 0.f;
        }
        ushort4 v[8];
#pragma unroll
        for (int k = 0; k < 8; ++k)
            v[k] = *(const ushort4*)(hbs + (size_t)idx[k] * 128 + c * 4);
#pragma unroll
        for (int k = 0; k < 8; ++k) {
            s0 = fmaf(bf16_to_f32(v[k].x), m[k], s0);
            s1 = fmaf(bf16_to_f32(v[k].y), m[k], s1);
            s2 = fmaf(bf16_to_f32(v[k].z), m[k], s2);
            s3 = fmaf(bf16_to_f32(v[k].w), m[k], s3);
        }
    }
    s0 += __shfl_xor(s0, 32);
    s1 += __shfl_xor(s1, 32);
    s2 += __shfl_xor(s2, 32);
    s3 += __shfl_xor(s3, 32);
    if (half == 0) {
        ushort4 hv, lv;
        hv.x = f32_to_bf16(s0); lv.x = f32_to_bf16(s0 - bf16_to_f32(hv.x));
        hv.y = f32_to_bf16(s1); lv.y = f32_to_bf16(s1 - bf16_to_f32(hv.y));
        hv.z = f32_to_bf16(s2); lv.z = f32_to_bf16(s2 - bf16_to_f32(hv.z));
        hv.w = f32_to_bf16(s3); lv.w = f32_to_bf16(s3 - bf16_to_f32(hv.w));
        *(ushort4*)(xo + (size_t)node * 256 + c * 4) = hv;
        *(ushort4*)(xo + (size_t)node * 256 + 128 + c * 4) = lv;
    }
}

// ---------------------------------------------------------------------------
// Weight split + frag-major repack (see R4 comment). Also absorbs two tiny
// one-off setup jobs to save dispatches: block 0 computes graph ranges
// (binary search on sorted gid), block 1 zeroes gsumAll.
// ---------------------------------------------------------------------------
__global__ __launch_bounds__(256) void bsplit_kernel(const float* __restrict__ Wa,
                                                     const float* __restrict__ Wb,
                                                     unsigned short* __restrict__ Bfrag,
                                                     const int* __restrict__ gid,
                                                     int* __restrict__ goff,
                                                     float* __restrict__ gsumAll) {
    if (blockIdx.x == 0) {   // graph ranges
        int g = threadIdx.x;
        int lo = 0, hi = NT;
        while (lo < hi) {
            int mid = (lo + hi) >> 1;
            if (gid[mid] < g) lo = mid + 1; else hi = mid;
        }
        goff[g] = lo;
        if (g == 0) goff[NG] = NT;
    }
    if (blockIdx.x == 1) {   // zero the BN-stats accumulators (4 x 256 floats)
#pragma unroll
        for (int i = 0; i < 4; ++i) gsumAll[i * 256 + threadIdx.x] = 0.f;
    }
    int slot = blockIdx.x >> 3;
    int sub = blockIdx.x & 7;
    const float* W = (slot < 4) ? (Wa + (size_t)slot * DIM * DIM)
                                : (Wb + (size_t)(slot - 4) * DIM * DIM);
    unsigned short* out = Bfrag + (size_t)slot * 32768;
    for (int i = 0; i < 16; ++i) {
        int e = sub * 4096 + i * 256 + threadIdx.x;
        int kphys = e >> 7, n = e & 127;
        int k = kphys & 127;
        float wv = W[k * 128 + n];
        unsigned short hi = f32_to_bf16(wv);
        unsigned short val = (kphys < 128) ? hi : f32_to_bf16(wv - bf16_to_f32(hi));
        int nt = n >> 5, nin = n & 31;
        int kcp = kphys >> 4, kgp = (kphys >> 3) & 1, jj = kphys & 7;
        out[(size_t)(((nt * 16 + kcp) * 64) + kgp * 32 + nin) * 8 + jj] = val;
    }
}

// ---------------------------------------------------------------------------
// MFMA GEMM, merged encoders: blockIdx.y = e, wi = e*2 + l. ASPLIT: A from
// precomputed bf16 hi/lo rows. !ASPLIT: A fp32 + per-block BN-param calc from
// gsumBase. STATS: column sum/sumsq. EMITB: also write bf16 mirror of C.
// ---------------------------------------------------------------------------
template <int ASPLIT, int STATS, int RELU, int EMITB>
__global__ __launch_bounds__(256) void fused_gemm_kernel(
        const void* __restrict__ Asrc, long aStride,
        const unsigned short* __restrict__ BfragBase, int bOff, int l,
        const float* __restrict__ biasBase,
        const float* __restrict__ gsumBase,
        const float* __restrict__ gammaBase, const float* __restrict__ betaBase,
        float* __restrict__ C, long cStride,
        unsigned short* __restrict__ CBout, long cbStride,
        float* __restrict__ gsumOutBase) {
    __shared__ char smem[65536 + 1024];
    unsigned short* sB = (unsigned short*)smem;
    float* sBNa = (float*)(smem + 65536);
    float* sBNb = sBNa + 128;
    const int ety = blockIdx.y, wi = ety * 2 + l;
    const unsigned short* Bfrag = BfragBase + (size_t)(bOff + wi) * 32768;
    const float* bias = biasBase + (size_t)wi * DIM;
    const int tid = threadIdx.x;
    const int w = tid >> 6, lane = tid & 63;
    const int nin = lane & 31, kg = lane >> 5;
    const int row0 = blockIdx.x * 128;
    const int myrow = row0 + w * 32 + nin;
    const int rowc = myrow < NT ? myrow : NT - 1;

    // stage whole B' into LDS
    {
        const uint4* Bg = (const uint4*)Bfrag;
        uint4* sB4 = (uint4*)smem;
#pragma unroll
        for (int i = 0; i < 16; ++i) sB4[tid + 256 * i] = Bg[tid + 256 * i];
    }

    s16x8 ahi[8], alo[8];
    if (ASPLIT) {
        const unsigned short* ar = (const unsigned short*)Asrc
                + (size_t)ety * aStride + (size_t)rowc * 256 + kg * 8;
#pragma unroll
        for (int kc = 0; kc < 8; ++kc) {
            ahi[kc] = *(const s16x8*)(ar + kc * 16);
            alo[kc] = *(const s16x8*)(ar + 128 + kc * 16);
        }
        __syncthreads();
    } else {
        const float* gsumIn = gsumBase + (size_t)wi * 256;
        if (tid < 128) {
            float mu = gsumIn[tid] * (1.0f / NT);
            float var = gsumIn[128 + tid] * (1.0f / NT) - mu * mu;
            float inv = rsqrtf(var + 1e-5f);
            float a = gammaBase[wi * DIM + tid] * inv;
            sBNa[tid] = a;
            sBNb[tid] = betaBase[wi * DIM + tid] - mu * a;
        }
        __syncthreads();   // sBN + B ready
        const float* yr = (const float*)Asrc + (size_t)ety * aStride
                + (size_t)rowc * 128 + kg * 8;
#pragma unroll
        for (int kc = 0; kc < 8; ++kc) {
            int c0 = kc * 16 + kg * 8;
            float4 y0 = *(const float4*)(yr + kc * 16);
            float4 y1 = *(const float4*)(yr + kc * 16 + 4);
            float4 a0 = *(const float4*)(sBNa + c0);
            float4 a1 = *(const float4*)(sBNa + c0 + 4);
            float4 b0 = *(const float4*)(sBNb + c0);
            float4 b1 = *(const float4*)(sBNb + c0 + 4);
            float t[8];
            t[0] = fmaxf(0.f, fmaf(y0.x, a0.x, b0.x));
            t[1] = fmaxf(0.f, fmaf(y0.y, a0.y, b0.y));
            t[2] = fmaxf(0.f, fmaf(y0.z, a0.z, b0.z));
            t[3] = fmaxf(0.f, fmaf(y0.w, a0.w, b0.w));
            t[4] = fmaxf(0.f, fmaf(y1.x, a1.x, b1.x));
            t[5] = fmaxf(0.f, fmaf(y1.y, a1.y, b1.y));
            t[6] = fmaxf(0.f, fmaf(y1.z, a1.z, b1.z));
            t[7] = fmaxf(0.f, fmaf(y1.w, a1.w, b1.w));
            union { s16x8 v; unsigned short u[8]; } H, L;
#pragma unroll
            for (int q = 0; q < 8; ++q) {
                H.u[q] = f32_to_bf16(t[q]);
                L.u[q] = f32_to_bf16(t[q] - bf16_to_f32(H.u[q]));
            }
            ahi[kc] = H.v; alo[kc] = L.v;
        }
    }

    f32x16 acc[4];
#pragma unroll
    for (int nt = 0; nt < 4; ++nt)
#pragma unroll
        for (int r = 0; r < 16; ++r) acc[nt][r] = 0.f;

#pragma unroll
    for (int nt = 0; nt < 4; ++nt) {
        const unsigned short* bp = sB + (size_t)(nt * 16) * 512 + lane * 8;
#pragma unroll
        for (int kc = 0; kc < 8; ++kc) {
            s16x8 b = *(const s16x8*)(bp + kc * 512);
            acc[nt] = __builtin_amdgcn_mfma_f32_32x32x16_bf16(ahi[kc], b, acc[nt], 0, 0, 0);
            acc[nt] = __builtin_amdgcn_mfma_f32_32x32x16_bf16(alo[kc], b, acc[nt], 0, 0, 0);
        }
#pragma unroll
        for (int kc = 0; kc < 8; ++kc) {
            s16x8 b = *(const s16x8*)(bp + (8 + kc) * 512);
            acc[nt] = __builtin_amdgcn_mfma_f32_32x32x16_bf16(ahi[kc], b, acc[nt], 0, 0, 0);
        }
    }

    float* Ce = C + (size_t)ety * cStride;
    unsigned short* CBe = EMITB ? (CBout + (size_t)ety * cbStride) : nullptr;
    const int rbase = row0 + w * 32 + 4 * kg;
#pragma unroll
    for (int nt = 0; nt < 4; ++nt) {
        int col = nt * 32 + nin;
        float bv = bias[col];
#pragma unroll
        for (int reg = 0; reg < 16; ++reg) {
            int gr = rbase + (reg & 3) + 8 * (reg >> 2);
            float v = acc[nt][reg] + bv;
            if (RELU) v = fmaxf(v, 0.f);
            if (gr < NT) {
                Ce[(size_t)gr * 128 + col] = v;
                if (EMITB) CBe[(size_t)gr * 128 + col] = f32_to_bf16(v);
            }
            acc[nt][reg] = (gr < NT) ? v : 0.f;
        }
    }

    if (STATS) {
        float* gsum = gsumOutBase + (size_t)wi * 256;
        __syncthreads();
        float* ls = (float*)smem;
        ls[tid] = 0.f;
        __syncthreads();
#pragma unroll
        for (int nt = 0; nt < 4; ++nt) {
            int col = nt * 32 + nin;
            float s = 0.f, q = 0.f;
#pragma unroll
            for (int reg = 0; reg < 16; ++reg) { float v = acc[nt][reg]; s += v; q += v * v; }
            atomicAdd(&ls[col], s);
            atomicAdd(&ls[128 + col], q);
        }
        __syncthreads();
        if (tid < 128) {
            atomicAdd(&gsum[tid], ls[tid]);
            atomicAdd(&gsum[128 + tid], ls[128 + tid]);
        }
    }
}

// ---------------------------------------------------------------------------
// Readout, merged encoders: blockIdx.y = e; 2 blocks/graph, partial sums.
// ---------------------------------------------------------------------------
__global__ __launch_bounds__(256) void readout_kernel(const float* __restrict__ bufH2,
                                                      const int* __restrict__ goff,
                                                      float* __restrict__ hgp) {
    int e = blockIdx.y;
    const float* h = bufH2 + (size_t)e * NT * 128;
    int colOff = e * 128;
    int g = blockIdx.x >> 1, h2 = blockIdx.x & 1;
    int c = threadIdx.x & 127, rr = threadIdx.x >> 7;
    int beg = goff[g], end = goff[g + 1];
    int n = beg + h2 * 2 + rr;
    float a0 = 0.f, a1 = 0.f, a2 = 0.f, a3 = 0.f;
    for (; n + 12 < end; n += 16) {
        a0 += h[(size_t)n * 128 + c];
        a1 += h[(size_t)(n + 4) * 128 + c];
        a2 += h[(size_t)(n + 8) * 128 + c];
        a3 += h[(size_t)(n + 12) * 128 + c];
    }
    for (; n < end; n += 4) a0 += h[(size_t)n * 128 + c];
    float acc = (a0 + a1) + (a2 + a3);
    __shared__ float ls[256];
    ls[threadIdx.x] = acc;
    __syncthreads();
    if (threadIdx.x < 128)
        hgp[(size_t)h2 * NG * 256 + g * 256 + colOff + c] = ls[c] + ls[128 + c];
}

// ---------------------------------------------------------------------------
__global__ __launch_bounds__(128) void mlp_kernel(const float* __restrict__ hgp,
                                                  const float* __restrict__ oW1,
                                                  const float* __restrict__ ob1,
                                                  const float* __restrict__ oW2,
                                                  const float* __restrict__ ob2,
                                                  const float* __restrict__ oW3,
                                                  const float* __restrict__ ob3,
                                                  float* __restrict__ out) {
    int g = blockIdx.x, t = threadIdx.x;
    __shared__ float sh[256];
    __shared__ float z[128];
    sh[t] = hgp[g * 256 + t] + hgp[(size_t)NG * 256 + g * 256 + t];
    sh[t + 128] = hgp[g * 256 + 128 + t] + hgp[(size_t)NG * 256 + g * 256 + 128 + t];
    __syncthreads();
    float acc = ob1[t];
    for (int k = 0; k < 256; ++k) acc = fmaf(sh[k], oW1[k * 128 + t], acc);
    float z1 = fmaxf(acc, 0.f);
    z[t] = z1;
    __syncthreads();
    acc = ob2[t];
    for (int k = 0; k < 128; ++k) acc = fmaf(z[k], oW2[k * 128 + t], acc);
    float z2 = fmaxf(acc, 0.f);
    float p = z2 * oW3[t];
    for (int off = 32; off > 0; off >>= 1) p += __shfl_down(p, off, 64);
    __shared__ float wsum[2];
    if ((t & 63) == 0) wsum[t >> 6] = p;
    __syncthreads();
    if (t == 0) out[g] = wsum[0] + wsum[1] + ob3[0];
}

// ---------------------------------------------------------------------------
extern "C" void kernel_launch(void* const* d_in, const int* in_sizes, int n_in,
                              void* d_out, int out_size, void* d_ws, size_t ws_size,
                              hipStream_t stream) {
    (void)in_sizes; (void)n_in; (void)out_size; (void)ws_size;
    const float* feats = (const float*)d_in[0];
    const int*   src   = (const int*)d_in[1];
    const int*   dst   = (const int*)d_in[2];
    const int*   gid   = (const int*)d_in[3];
    const float* epsp  = (const float*)d_in[5];
    const float* Wa    = (const float*)d_in[6];
    const float* ba    = (const float*)d_in[7];
    const float* bng   = (const float*)d_in[8];
    const float* bnb   = (const float*)d_in[9];
    const float* Wb    = (const float*)d_in[10];
    const float* bb    = (const float*)d_in[11];
    const float* oW1   = (const float*)d_in[12];
    const float* ob1   = (const float*)d_in[13];
    const float* oW2   = (const float*)d_in[14];
    const float* ob2   = (const float*)d_in[15];
    const float* oW3   = (const float*)d_in[16];
    const float* ob3   = (const float*)d_in[17];
    float* out = (float*)d_out;

    char* p = (char*)d_ws;
    auto carve = [&](size_t bytes) -> void* {
        void* r = (void*)p;
        p += (bytes + 255) & ~(size_t)255;
        return r;
    };
    unsigned short* Asplit2 = (unsigned short*)carve((size_t)2 * NT * 256 * 2);
    float* bufY2   = (float*)carve((size_t)2 * NT * DIM * 4);
    float* bufH2   = (float*)carve((size_t)2 * NT * DIM * 4);
    unsigned short* featsB = (unsigned short*)carve((size_t)NT * DIM * 2);
    unsigned short* hB2    = (unsigned short*)carve((size_t)2 * NT * DIM * 2);
    unsigned short* Bfrag  = (unsigned short*)carve((size_t)8 * 32768 * 2);
    int*   esrc2    = (int*)carve((size_t)2 * NE * 4);
    unsigned int* part2 = (unsigned int*)carve((size_t)2 * NE * 4);
    int*   hcoarse2 = (int*)carve((size_t)2 * HCN * 4);
    int*   offbuf2  = (int*)carve((size_t)2 * HCN * 4);
    int*   bb2      = (int*)carve((size_t)2 * (NB + 1) * 4);
    int*   indptr2  = (int*)carve((size_t)2 * (NT + 1) * 4);
    int*   goff     = (int*)carve((size_t)(NG + 1) * 4);
    float* gsumAll  = (float*)carve((size_t)4 * 256 * 4);  // wi x (sum|sumsq)
    float* hgp      = (float*)carve((size_t)2 * NG * 256 * 4);

    const int CB = (NT * 32 + 255) / 256;

    // bsplit also computes graph ranges (block 0) and zeroes gsumAll (block 1)
    bsplit_kernel<<<64, 256, 0, stream>>>(Wa, Wb, Bfrag, gid, goff, gsumAll);
    tobf16_kernel<<<CB, 256, 0, stream>>>(feats, featsB);

    // CSR for both edge types, up front
    csr_part_hist_kernel<<<dim3(PB, 2), 256, 0, stream>>>(dst, hcoarse2);
    csr_scan_kernel<<<2, 1024, 0, stream>>>(hcoarse2, offbuf2, bb2, indptr2);
    csr_scatter_kernel<<<dim3(PB, 2), 256, 0, stream>>>(src, dst, offbuf2, part2);
    csr_finalize_kernel<<<dim3(NB, 2), 256, 0, stream>>>(part2, bb2, indptr2, esrc2);

    for (int l = 0; l < 2; ++l) {
        // aggregation for both encoders in one launch
        if (l == 0)
            agg_split_kernel<<<dim3((NT + 3) / 4, 2), 256, 0, stream>>>(
                feats, 0, featsB, 0, indptr2, esrc2, epsp, l, Asplit2);
        else
            agg_split_kernel<<<dim3((NT + 3) / 4, 2), 256, 0, stream>>>(
                bufH2, (long)NT * DIM, hB2, (long)NT * DIM,
                indptr2, esrc2, epsp, l, Asplit2);
        // GEMM1 both encoders: A from Asplit, stats for BN
        fused_gemm_kernel<1, 1, 0, 0><<<dim3(GEMM_B, 2), 256, 0, stream>>>(
            Asplit2, (long)NT * 256, Bfrag, 0, l, ba,
            nullptr, nullptr, nullptr,
            bufY2, (long)NT * DIM, nullptr, 0, gsumAll);
        // GEMM2 both encoders: fused BN-param + BN+ReLU (+bf16 mirror on l==0)
        if (l == 0)
            fused_gemm_kernel<0, 0, 1, 1><<<dim3(GEMM_B, 2), 256, 0, stream>>>(
                bufY2, (long)NT * DIM, Bfrag, 4, l, bb,
                gsumAll, bng, bnb,
                bufH2, (long)NT * DIM, hB2, (long)NT * DIM, nullptr);
        else
            fused_gemm_kernel<0, 0, 0, 0><<<dim3(GEMM_B, 2), 256, 0, stream>>>(
                bufY2, (long)NT * DIM, Bfrag, 4, l, bb,
                gsumAll, bng, bnb,
                bufH2, (long)NT * DIM, nullptr, 0, nullptr);
    }
    readout_kernel<<<dim3(NG * 2, 2), 256, 0, stream>>>(bufH2, goff, hgp);
    mlp_kernel<<<NG, 128, 0, stream>>>(hgp, oW1, ob1, oW2, ob2, oW3, ob3, out);
}

// Round 12
// 513.989 us; speedup vs baseline: 1.0404x; 1.0404x over previous
//
#include <hip/hip_runtime.h>

#define NT 50000   // nodes
#define NE 800000  // edges per edge-type
#define NG 256     // graphs
#define DIM 128
#define GEMM_B ((NT + 127) / 128)    // 391 MFMA-GEMM blocks per encoder

// CSR-build partition constants
#define NB 128                        // coarse dst buckets
#define BW 391                        // bucket width: 128*391 = 50048 >= NT
#define PB 196                        // partition blocks
#define PCH 4096                      // edges per partition block
#define HCN (NB * PB)                 // 25088

typedef short s16x8 __attribute__((ext_vector_type(8)));
typedef float f32x16 __attribute__((ext_vector_type(16)));

__device__ __forceinline__ unsigned short f32_to_bf16(float f) {
    unsigned int u = __float_as_uint(f);
    u += 0x7FFFu + ((u >> 16) & 1u);   // round-to-nearest-even
    return (unsigned short)(u >> 16);
}
__device__ __forceinline__ float bf16_to_f32(unsigned short h) {
    return __uint_as_float(((unsigned int)h) << 16);
}

// ---------------------------------------------------------------------------
__global__ __launch_bounds__(256) void tobf16_kernel(const float* __restrict__ in,
                                                     unsigned short* __restrict__ out) {
    int i = blockIdx.x * 256 + threadIdx.x;
    if (i >= NT * 32) return;
    float4 v = ((const float4*)in)[i];
    ushort4 o;
    o.x = f32_to_bf16(v.x); o.y = f32_to_bf16(v.y);
    o.z = f32_to_bf16(v.z); o.w = f32_to_bf16(v.w);
    ((ushort4*)out)[i] = o;
}

// ---------------------------------------------------------------------------
// CSR build (both edge types at once, blockIdx.y = e), 2-level counting sort
// ---------------------------------------------------------------------------
__global__ __launch_bounds__(256) void csr_part_hist_kernel(
        const int* __restrict__ dstAll, int* __restrict__ hcoarseAll) {
    const int* dst = dstAll + (size_t)blockIdx.y * NE;
    int* hcoarse = hcoarseAll + (size_t)blockIdx.y * HCN;
    __shared__ int h[NB];
    if (threadIdx.x < NB) h[threadIdx.x] = 0;
    __syncthreads();
#pragma unroll
    for (int i = 0; i < PCH / 256; ++i) {
        int e = blockIdx.x * PCH + i * 256 + threadIdx.x;
        if (e < NE) atomicAdd(&h[dst[e] / BW], 1);
    }
    __syncthreads();
    if (threadIdx.x < NB)
        hcoarse[threadIdx.x * PB + blockIdx.x] = h[threadIdx.x];
}

__global__ __launch_bounds__(1024) void csr_scan_kernel(
        const int* __restrict__ hcoarseAll, int* __restrict__ offAll,
        int* __restrict__ bucketBaseAll, int* __restrict__ indptrAll) {
    const int* hcoarse = hcoarseAll + (size_t)blockIdx.x * HCN;
    int* off = offAll + (size_t)blockIdx.x * HCN;
    int* bucketBase = bucketBaseAll + (size_t)blockIdx.x * (NB + 1);
    int* indptr = indptrAll + (size_t)blockIdx.x * (NT + 1);
    __shared__ int ps[1024];
    int t = threadIdx.x;
    const int CH = (HCN + 1023) / 1024;  // 25
    int beg = t * CH, end = beg + CH; if (end > HCN) end = HCN;
    int s = 0;
    for (int i = beg; i < end; ++i) s += hcoarse[i];
    ps[t] = s;
    __syncthreads();
    for (int o = 1; o < 1024; o <<= 1) {
        int v = (t >= o) ? ps[t - o] : 0;
        __syncthreads();
        ps[t] += v;
        __syncthreads();
    }
    int run = (t == 0) ? 0 : ps[t - 1];
    for (int i = beg; i < end; ++i) {
        off[i] = run;
        if (i % PB == 0) bucketBase[i / PB] = run;
        run += hcoarse[i];
    }
    if (t == 1023) bucketBase[NB] = NE;
    if (t == 0) indptr[NT] = NE;
}

__global__ __launch_bounds__(256) void csr_scatter_kernel(
        const int* __restrict__ srcAll, const int* __restrict__ dstAll,
        const int* __restrict__ offAll, unsigned int* __restrict__ partAll) {
    const int* src = srcAll + (size_t)blockIdx.y * NE;
    const int* dst = dstAll + (size_t)blockIdx.y * NE;
    const int* off = offAll + (size_t)blockIdx.y * HCN;
    unsigned int* part = partAll + (size_t)blockIdx.y * NE;
    __shared__ int cur[NB];
    if (threadIdx.x < NB) cur[threadIdx.x] = off[threadIdx.x * PB + blockIdx.x];
    __syncthreads();
#pragma unroll
    for (int i = 0; i < PCH / 256; ++i) {
        int e = blockIdx.x * PCH + i * 256 + threadIdx.x;
        if (e < NE) {
            int d = dst[e];
            int b = d / BW;
            int pos = atomicAdd(&cur[b], 1);
            part[pos] = ((unsigned int)(d - b * BW) << 16) | (unsigned int)src[e];
        }
    }
}

__global__ __launch_bounds__(256) void csr_finalize_kernel(
        const unsigned int* __restrict__ partAll,
        const int* __restrict__ bucketBaseAll,
        int* __restrict__ indptrAll, int* __restrict__ esrcAll) {
    const unsigned int* part = partAll + (size_t)blockIdx.y * NE;
    const int* bucketBase = bucketBaseAll + (size_t)blockIdx.y * (NB + 1);
    int* indptr = indptrAll + (size_t)blockIdx.y * (NT + 1);
    int* esrc = esrcAll + (size_t)blockIdx.y * NE;
    __shared__ int cnt[512];
    __shared__ int excl[512];
    __shared__ int ps[256];
    __shared__ int cur[BW + 1];
    int b = blockIdx.x, t = threadIdx.x;
    int base = bucketBase[b];
    int n = bucketBase[b + 1] - base;
    cnt[t] = 0; cnt[t + 256] = 0;
    for (int j = t; j <= BW; j += 256) cur[j] = 0;
    __syncthreads();
    for (int i = t; i < n; i += 256) atomicAdd(&cnt[part[base + i] >> 16], 1);
    __syncthreads();
    int a0 = cnt[2 * t], a1 = cnt[2 * t + 1];
    ps[t] = a0 + a1;
    __syncthreads();
    for (int o = 1; o < 256; o <<= 1) {
        int v = (t >= o) ? ps[t - o] : 0;
        __syncthreads();
        ps[t] += v;
        __syncthreads();
    }
    int before = (t == 0) ? 0 : ps[t - 1];
    excl[2 * t] = before;
    excl[2 * t + 1] = before + a0;
    __syncthreads();
    int node0 = b * BW;
    for (int j = t; j < BW; j += 256) {
        int gn = node0 + j;
        if (gn < NT) indptr[gn] = base + excl[j];
    }
    for (int i = t; i < n; i += 256) {
        unsigned int pk = part[base + i];
        int dl = pk >> 16;
        int pos = atomicAdd(&cur[dl], 1);
        esrc[base + excl[dl] + pos] = (int)(pk & 0xFFFFu);
    }
}

// ---------------------------------------------------------------------------
// Aggregation + bf16 hi/lo split. One node per wave; half-wave hw owns edges
// [j+8hw, j+8hw+8) of each 16-edge chunk. Full chunks unmasked; one masked
// 8-deep tail chunk (depth stays 8 for every node — R9 lesson). At ~6.1 TB/s
// effective gather service this kernel is at the memory-system ceiling (R11).
// ---------------------------------------------------------------------------
__global__ __launch_bounds__(256) void agg_split_kernel(
        const float* __restrict__ h, long hStride,
        const unsigned short* __restrict__ hb, long hbStride,
        const int* __restrict__ indptr2, const int* __restrict__ esrc2,
        const float* __restrict__ eps_p, int l,
        unsigned short* __restrict__ xout2) {
    int e = blockIdx.y;
    const float* hs = h + (size_t)e * hStride;
    const unsigned short* hbs = hb + (size_t)e * hbStride;
    const int* indptr = indptr2 + (size_t)e * (NT + 1);
    const int* esrc = esrc2 + (size_t)e * NE;
    unsigned short* xo = xout2 + (size_t)e * NT * 256;
    int node = blockIdx.x * 4 + (threadIdx.x >> 6);   // 1 node per wave
    if (node >= NT) return;
    int lane = threadIdx.x & 63;
    int half = lane >> 5, c = lane & 31;
    float s0 = 0.f, s1 = 0.f, s2 = 0.f, s3 = 0.f;
    if (half == 0) {
        float e1 = 1.0f + eps_p[e * 2 + l];
        float4 a = ((const float4*)hs)[(size_t)node * 32 + c];
        s0 = e1 * a.x; s1 = e1 * a.y; s2 = e1 * a.z; s3 = e1 * a.w;
    }
    int beg = indptr[node], end = indptr[node + 1];
    int deg = end - beg;
    int endFull = beg + (deg & ~15);
    int j = beg;
    for (; j < endFull; j += 16) {              // unmasked full chunks
        int b0 = j + half * 8;
        int idx[8];
#pragma unroll
        for (int k = 0; k < 8; ++k) idx[k] = esrc[b0 + k];
        ushort4 v[8];
#pragma unroll
        for (int k = 0; k < 8; ++k)
            v[k] = *(const ushort4*)(hbs + (size_t)idx[k] * 128 + c * 4);
#pragma unroll
        for (int k = 0; k < 8; ++k) {
            s0 += bf16_to_f32(v[k].x);
            s1 += bf16_to_f32(v[k].y);
            s2 += bf16_to_f32(v[k].z);
            s3 += bf16_to_f32(v[k].w);
        }
    }
    if (j < end) {                              // one masked 8-deep tail chunk
        int b0 = j + half * 8;
        int idx[8];
        float m[8];
#pragma unroll
        for (int k = 0; k < 8; ++k) {
            int jj = b0 + k;
            int ok = jj < end;
            idx[k] = esrc[ok ? jj : end - 1];   // clamp valid (deg > 0 here)
            m[k] = ok ? 1.f : 0.f;
        }
        ushort4 v[8];
#pragma unroll
        for (int k = 0; k < 8; ++k)
            v[k] = *(const ushort4*)(hbs + (size_t)idx[k] * 128 + c * 4);
#pragma unroll
        for (int k = 0; k < 8; ++k) {
            s0 = fmaf(bf16_to_f32(v[k].x), m[k], s0);
            s1 = fmaf(bf16_to_f32(v[k].y), m[k], s1);
            s2 = fmaf(bf16_to_f32(v[k].z), m[k], s2);
            s3 = fmaf(bf16_to_f32(v[k].w), m[k], s3);
        }
    }
    s0 += __shfl_xor(s0, 32);
    s1 += __shfl_xor(s1, 32);
    s2 += __shfl_xor(s2, 32);
    s3 += __shfl_xor(s3, 32);
    if (half == 0) {
        ushort4 hv, lv;
        hv.x = f32_to_bf16(s0); lv.x = f32_to_bf16(s0 - bf16_to_f32(hv.x));
        hv.y = f32_to_bf16(s1); lv.y = f32_to_bf16(s1 - bf16_to_f32(hv.y));
        hv.z = f32_to_bf16(s2); lv.z = f32_to_bf16(s2 - bf16_to_f32(hv.z));
        hv.w = f32_to_bf16(s3); lv.w = f32_to_bf16(s3 - bf16_to_f32(hv.w));
        *(ushort4*)(xo + (size_t)node * 256 + c * 4) = hv;
        *(ushort4*)(xo + (size_t)node * 256 + 128 + c * 4) = lv;
    }
}

// ---------------------------------------------------------------------------
// Weight split + frag-major repack (see R4 comment). Block 0 also computes
// graph ranges, block 1 zeroes the BN-stats accumulators.
// ---------------------------------------------------------------------------
__global__ __launch_bounds__(256) void bsplit_kernel(const float* __restrict__ Wa,
                                                     const float* __restrict__ Wb,
                                                     unsigned short* __restrict__ Bfrag,
                                                     const int* __restrict__ gid,
                                                     int* __restrict__ goff,
                                                     float* __restrict__ gsumAll) {
    if (blockIdx.x == 0) {   // graph ranges
        int g = threadIdx.x;
        int lo = 0, hi = NT;
        while (lo < hi) {
            int mid = (lo + hi) >> 1;
            if (gid[mid] < g) lo = mid + 1; else hi = mid;
        }
        goff[g] = lo;
        if (g == 0) goff[NG] = NT;
    }
    if (blockIdx.x == 1) {   // zero the BN-stats accumulators (4 x 256 floats)
#pragma unroll
        for (int i = 0; i < 4; ++i) gsumAll[i * 256 + threadIdx.x] = 0.f;
    }
    int slot = blockIdx.x >> 3;
    int sub = blockIdx.x & 7;
    const float* W = (slot < 4) ? (Wa + (size_t)slot * DIM * DIM)
                                : (Wb + (size_t)(slot - 4) * DIM * DIM);
    unsigned short* out = Bfrag + (size_t)slot * 32768;
    for (int i = 0; i < 16; ++i) {
        int e = sub * 4096 + i * 256 + threadIdx.x;
        int kphys = e >> 7, n = e & 127;
        int k = kphys & 127;
        float wv = W[k * 128 + n];
        unsigned short hi = f32_to_bf16(wv);
        unsigned short val = (kphys < 128) ? hi : f32_to_bf16(wv - bf16_to_f32(hi));
        int nt = n >> 5, nin = n & 31;
        int kcp = kphys >> 4, kgp = (kphys >> 3) & 1, jj = kphys & 7;
        out[(size_t)(((nt * 16 + kcp) * 64) + kgp * 32 + nin) * 8 + jj] = val;
    }
}

// ---------------------------------------------------------------------------
// MFMA GEMM, merged encoders: blockIdx.y = e, wi = e*2 + l. ASPLIT: A from
// precomputed bf16 hi/lo rows. !ASPLIT: A fp32 + per-block BN-param calc.
// STATS: column sum/sumsq. EMITB: also write bf16 mirror of C.
// FUSERO: final layer — skip the C write entirely and accumulate the
// per-graph readout (segment sum) directly from registers: graph_ids is
// sorted, each lane's 16 rows are visited in increasing row order, so a
// run-flush emits ~2 atomicAdds per (lane, col-group) into hg[g, col].
// ---------------------------------------------------------------------------
template <int ASPLIT, int STATS, int RELU, int EMITB, int FUSERO>
__global__ __launch_bounds__(256) void fused_gemm_kernel(
        const void* __restrict__ Asrc, long aStride,
        const unsigned short* __restrict__ BfragBase, int bOff, int l,
        const float* __restrict__ biasBase,
        const float* __restrict__ gsumBase,
        const float* __restrict__ gammaBase, const float* __restrict__ betaBase,
        float* __restrict__ C, long cStride,
        unsigned short* __restrict__ CBout, long cbStride,
        float* __restrict__ gsumOutBase,
        const int* __restrict__ gidIn, float* __restrict__ hgpOut) {
    __shared__ char smem[65536 + 1024 + 512];
    unsigned short* sB = (unsigned short*)smem;
    float* sBNa = (float*)(smem + 65536);
    float* sBNb = sBNa + 128;
    int* sgid = (int*)(smem + 65536 + 1024);
    const int ety = blockIdx.y, wi = ety * 2 + l;
    const unsigned short* Bfrag = BfragBase + (size_t)(bOff + wi) * 32768;
    const float* bias = biasBase + (size_t)wi * DIM;
    const int tid = threadIdx.x;
    const int w = tid >> 6, lane = tid & 63;
    const int nin = lane & 31, kg = lane >> 5;
    const int row0 = blockIdx.x * 128;
    const int myrow = row0 + w * 32 + nin;
    const int rowc = myrow < NT ? myrow : NT - 1;

    // stage whole B' into LDS
    {
        const uint4* Bg = (const uint4*)Bfrag;
        uint4* sB4 = (uint4*)smem;
#pragma unroll
        for (int i = 0; i < 16; ++i) sB4[tid + 256 * i] = Bg[tid + 256 * i];
    }

    s16x8 ahi[8], alo[8];
    if (ASPLIT) {
        const unsigned short* ar = (const unsigned short*)Asrc
                + (size_t)ety * aStride + (size_t)rowc * 256 + kg * 8;
#pragma unroll
        for (int kc = 0; kc < 8; ++kc) {
            ahi[kc] = *(const s16x8*)(ar + kc * 16);
            alo[kc] = *(const s16x8*)(ar + 128 + kc * 16);
        }
        __syncthreads();
    } else {
        const float* gsumIn = gsumBase + (size_t)wi * 256;
        if (tid < 128) {
            float mu = gsumIn[tid] * (1.0f / NT);
            float var = gsumIn[128 + tid] * (1.0f / NT) - mu * mu;
            float inv = rsqrtf(var + 1e-5f);
            float a = gammaBase[wi * DIM + tid] * inv;
            sBNa[tid] = a;
            sBNb[tid] = betaBase[wi * DIM + tid] - mu * a;
            if (FUSERO) {
                int rr = row0 + tid;
                sgid[tid] = gidIn[rr < NT ? rr : NT - 1];
            }
        }
        __syncthreads();   // sBN + sgid + B ready
        const float* yr = (const float*)Asrc + (size_t)ety * aStride
                + (size_t)rowc * 128 + kg * 8;
#pragma unroll
        for (int kc = 0; kc < 8; ++kc) {
            int c0 = kc * 16 + kg * 8;
            float4 y0 = *(const float4*)(yr + kc * 16);
            float4 y1 = *(const float4*)(yr + kc * 16 + 4);
            float4 a0 = *(const float4*)(sBNa + c0);
            float4 a1 = *(const float4*)(sBNa + c0 + 4);
            float4 b0 = *(const float4*)(sBNb + c0);
            float4 b1 = *(const float4*)(sBNb + c0 + 4);
            float t[8];
            t[0] = fmaxf(0.f, fmaf(y0.x, a0.x, b0.x));
            t[1] = fmaxf(0.f, fmaf(y0.y, a0.y, b0.y));
            t[2] = fmaxf(0.f, fmaf(y0.z, a0.z, b0.z));
            t[3] = fmaxf(0.f, fmaf(y0.w, a0.w, b0.w));
            t[4] = fmaxf(0.f, fmaf(y1.x, a1.x, b1.x));
            t[5] = fmaxf(0.f, fmaf(y1.y, a1.y, b1.y));
            t[6] = fmaxf(0.f, fmaf(y1.z, a1.z, b1.z));
            t[7] = fmaxf(0.f, fmaf(y1.w, a1.w, b1.w));
            union { s16x8 v; unsigned short u[8]; } H, L;
#pragma unroll
            for (int q = 0; q < 8; ++q) {
                H.u[q] = f32_to_bf16(t[q]);
                L.u[q] = f32_to_bf16(t[q] - bf16_to_f32(H.u[q]));
            }
            ahi[kc] = H.v; alo[kc] = L.v;
        }
    }

    f32x16 acc[4];
#pragma unroll
    for (int nt = 0; nt < 4; ++nt)
#pragma unroll
        for (int r = 0; r < 16; ++r) acc[nt][r] = 0.f;

#pragma unroll
    for (int nt = 0; nt < 4; ++nt) {
        const unsigned short* bp = sB + (size_t)(nt * 16) * 512 + lane * 8;
#pragma unroll
        for (int kc = 0; kc < 8; ++kc) {
            s16x8 b = *(const s16x8*)(bp + kc * 512);
            acc[nt] = __builtin_amdgcn_mfma_f32_32x32x16_bf16(ahi[kc], b, acc[nt], 0, 0, 0);
            acc[nt] = __builtin_amdgcn_mfma_f32_32x32x16_bf16(alo[kc], b, acc[nt], 0, 0, 0);
        }
#pragma unroll
        for (int kc = 0; kc < 8; ++kc) {
            s16x8 b = *(const s16x8*)(bp + (8 + kc) * 512);
            acc[nt] = __builtin_amdgcn_mfma_f32_32x32x16_bf16(ahi[kc], b, acc[nt], 0, 0, 0);
        }
    }

    if (FUSERO) {
        // readout fused: segment-sum rows into hg[g, ety*128 + col]
#pragma unroll
        for (int nt = 0; nt < 4; ++nt) {
            int col = nt * 32 + nin;
            float bv = bias[col];
            float run = 0.f;
            int curg = -1;
#pragma unroll
            for (int reg = 0; reg < 16; ++reg) {
                int lr = w * 32 + 4 * kg + (reg & 3) + 8 * (reg >> 2);
                int gr = row0 + lr;
                float v = acc[nt][reg] + bv;
                int g = sgid[lr];
                if (g != curg) {
                    if (curg >= 0)
                        atomicAdd(&hgpOut[(size_t)curg * 256 + ety * 128 + col], run);
                    curg = g;
                    run = 0.f;
                }
                run += (gr < NT) ? v : 0.f;
            }
            if (curg >= 0)
                atomicAdd(&hgpOut[(size_t)curg * 256 + ety * 128 + col], run);
        }
        return;
    }

    float* Ce = C + (size_t)ety * cStride;
    unsigned short* CBe = EMITB ? (CBout + (size_t)ety * cbStride) : nullptr;
    const int rbase = row0 + w * 32 + 4 * kg;
#pragma unroll
    for (int nt = 0; nt < 4; ++nt) {
        int col = nt * 32 + nin;
        float bv = bias[col];
#pragma unroll
        for (int reg = 0; reg < 16; ++reg) {
            int gr = rbase + (reg & 3) + 8 * (reg >> 2);
            float v = acc[nt][reg] + bv;
            if (RELU) v = fmaxf(v, 0.f);
            if (gr < NT) {
                Ce[(size_t)gr * 128 + col] = v;
                if (EMITB) CBe[(size_t)gr * 128 + col] = f32_to_bf16(v);
            }
            acc[nt][reg] = (gr < NT) ? v : 0.f;
        }
    }

    if (STATS) {
        float* gsum = gsumOutBase + (size_t)wi * 256;
        __syncthreads();
        float* ls = (float*)smem;
        ls[tid] = 0.f;
        __syncthreads();
#pragma unroll
        for (int nt = 0; nt < 4; ++nt) {
            int col = nt * 32 + nin;
            float s = 0.f, q = 0.f;
#pragma unroll
            for (int reg = 0; reg < 16; ++reg) { float v = acc[nt][reg]; s += v; q += v * v; }
            atomicAdd(&ls[col], s);
            atomicAdd(&ls[128 + col], q);
        }
        __syncthreads();
        if (tid < 128) {
            atomicAdd(&gsum[tid], ls[tid]);
            atomicAdd(&gsum[128 + tid], ls[128 + tid]);
        }
    }
}

// ---------------------------------------------------------------------------
__global__ __launch_bounds__(128) void mlp_kernel(const float* __restrict__ hgp,
                                                  const float* __restrict__ oW1,
                                                  const float* __restrict__ ob1,
                                                  const float* __restrict__ oW2,
                                                  const float* __restrict__ ob2,
                                                  const float* __restrict__ oW3,
                                                  const float* __restrict__ ob3,
                                                  float* __restrict__ out) {
    int g = blockIdx.x, t = threadIdx.x;
    __shared__ float sh[256];
    __shared__ float z[128];
    sh[t] = hgp[g * 256 + t];
    sh[t + 128] = hgp[g * 256 + 128 + t];
    __syncthreads();
    float acc = ob1[t];
    for (int k = 0; k < 256; ++k) acc = fmaf(sh[k], oW1[k * 128 + t], acc);
    float z1 = fmaxf(acc, 0.f);
    z[t] = z1;
    __syncthreads();
    acc = ob2[t];
    for (int k = 0; k < 128; ++k) acc = fmaf(z[k], oW2[k * 128 + t], acc);
    float z2 = fmaxf(acc, 0.f);
    float p = z2 * oW3[t];
    for (int off = 32; off > 0; off >>= 1) p += __shfl_down(p, off, 64);
    __shared__ float wsum[2];
    if ((t & 63) == 0) wsum[t >> 6] = p;
    __syncthreads();
    if (t == 0) out[g] = wsum[0] + wsum[1] + ob3[0];
}

// ---------------------------------------------------------------------------
extern "C" void kernel_launch(void* const* d_in, const int* in_sizes, int n_in,
                              void* d_out, int out_size, void* d_ws, size_t ws_size,
                              hipStream_t stream) {
    (void)in_sizes; (void)n_in; (void)out_size; (void)ws_size;
    const float* feats = (const float*)d_in[0];
    const int*   src   = (const int*)d_in[1];
    const int*   dst   = (const int*)d_in[2];
    const int*   gid   = (const int*)d_in[3];
    const float* epsp  = (const float*)d_in[5];
    const float* Wa    = (const float*)d_in[6];
    const float* ba    = (const float*)d_in[7];
    const float* bng   = (const float*)d_in[8];
    const float* bnb   = (const float*)d_in[9];
    const float* Wb    = (const float*)d_in[10];
    const float* bb    = (const float*)d_in[11];
    const float* oW1   = (const float*)d_in[12];
    const float* ob1   = (const float*)d_in[13];
    const float* oW2   = (const float*)d_in[14];
    const float* ob2   = (const float*)d_in[15];
    const float* oW3   = (const float*)d_in[16];
    const float* ob3   = (const float*)d_in[17];
    float* out = (float*)d_out;

    char* p = (char*)d_ws;
    auto carve = [&](size_t bytes) -> void* {
        void* r = (void*)p;
        p += (bytes + 255) & ~(size_t)255;
        return r;
    };
    unsigned short* Asplit2 = (unsigned short*)carve((size_t)2 * NT * 256 * 2);
    float* bufY2   = (float*)carve((size_t)2 * NT * DIM * 4);
    float* bufH2   = (float*)carve((size_t)2 * NT * DIM * 4);
    unsigned short* featsB = (unsigned short*)carve((size_t)NT * DIM * 2);
    unsigned short* hB2    = (unsigned short*)carve((size_t)2 * NT * DIM * 2);
    unsigned short* Bfrag  = (unsigned short*)carve((size_t)8 * 32768 * 2);
    int*   esrc2    = (int*)carve((size_t)2 * NE * 4);
    unsigned int* part2 = (unsigned int*)carve((size_t)2 * NE * 4);
    int*   hcoarse2 = (int*)carve((size_t)2 * HCN * 4);
    int*   offbuf2  = (int*)carve((size_t)2 * HCN * 4);
    int*   bb2      = (int*)carve((size_t)2 * (NB + 1) * 4);
    int*   indptr2  = (int*)carve((size_t)2 * (NT + 1) * 4);
    int*   goff     = (int*)carve((size_t)(NG + 1) * 4);
    float* gsumAll  = (float*)carve((size_t)4 * 256 * 4);  // wi x (sum|sumsq)
    float* hgp      = (float*)carve((size_t)NG * 256 * 4);

    const int CB = (NT * 32 + 255) / 256;

    // bsplit also computes graph ranges (block 0) and zeroes gsumAll (block 1)
    bsplit_kernel<<<64, 256, 0, stream>>>(Wa, Wb, Bfrag, gid, goff, gsumAll);
    tobf16_kernel<<<CB, 256, 0, stream>>>(feats, featsB);
    hipMemsetAsync(hgp, 0, (size_t)NG * 256 * 4, stream);  // readout accumulator

    // CSR for both edge types, up front
    csr_part_hist_kernel<<<dim3(PB, 2), 256, 0, stream>>>(dst, hcoarse2);
    csr_scan_kernel<<<2, 1024, 0, stream>>>(hcoarse2, offbuf2, bb2, indptr2);
    csr_scatter_kernel<<<dim3(PB, 2), 256, 0, stream>>>(src, dst, offbuf2, part2);
    csr_finalize_kernel<<<dim3(NB, 2), 256, 0, stream>>>(part2, bb2, indptr2, esrc2);

    for (int l = 0; l < 2; ++l) {
        // aggregation for both encoders in one launch
        if (l == 0)
            agg_split_kernel<<<dim3((NT + 3) / 4, 2), 256, 0, stream>>>(
                feats, 0, featsB, 0, indptr2, esrc2, epsp, l, Asplit2);
        else
            agg_split_kernel<<<dim3((NT + 3) / 4, 2), 256, 0, stream>>>(
                bufH2, (long)NT * DIM, hB2, (long)NT * DIM,
                indptr2, esrc2, epsp, l, Asplit2);
        // GEMM1 both encoders: A from Asplit, stats for BN
        fused_gemm_kernel<1, 1, 0, 0, 0><<<dim3(GEMM_B, 2), 256, 0, stream>>>(
            Asplit2, (long)NT * 256, Bfrag, 0, l, ba,
            nullptr, nullptr, nullptr,
            bufY2, (long)NT * DIM, nullptr, 0, gsumAll,
            nullptr, nullptr);
        // GEMM2 both encoders: fused BN-param + BN on A.
        //  l==0: +ReLU, write bufH + bf16 mirror (consumed by agg l=1)
        //  l==1: fused per-graph readout (no C materialization at all)
        if (l == 0)
            fused_gemm_kernel<0, 0, 1, 1, 0><<<dim3(GEMM_B, 2), 256, 0, stream>>>(
                bufY2, (long)NT * DIM, Bfrag, 4, l, bb,
                gsumAll, bng, bnb,
                bufH2, (long)NT * DIM, hB2, (long)NT * DIM, nullptr,
                nullptr, nullptr);
        else
            fused_gemm_kernel<0, 0, 0, 0, 1><<<dim3(GEMM_B, 2), 256, 0, stream>>>(
                bufY2, (long)NT * DIM, Bfrag, 4, l, bb,
                gsumAll, bng, bnb,
                nullptr, 0, nullptr, 0, nullptr,
                gid, hgp);
    }
    mlp_kernel<<<NG, 128, 0, stream>>>(hgp, oW1, ob1, oW2, ob2, oW3, ob3, out);
}

// Round 13
// 511.326 us; speedup vs baseline: 1.0458x; 1.0052x over previous
//
#include <hip/hip_runtime.h>

#define NT 50000   // nodes
#define NE 800000  // edges per edge-type
#define NG 256     // graphs
#define DIM 128
#define GEMM_B ((NT + 127) / 128)    // 391 MFMA-GEMM blocks per encoder

// CSR-build partition constants
#define NB 128                        // coarse dst buckets
#define BW 391                        // bucket width: 128*391 = 50048 >= NT
#define PB 196                        // partition blocks
#define PCH 4096                      // edges per partition block
#define HCN (NB * PB)                 // 25088

typedef short s16x8 __attribute__((ext_vector_type(8)));
typedef float f32x16 __attribute__((ext_vector_type(16)));

__device__ __forceinline__ unsigned short f32_to_bf16(float f) {
    unsigned int u = __float_as_uint(f);
    u += 0x7FFFu + ((u >> 16) & 1u);   // round-to-nearest-even
    return (unsigned short)(u >> 16);
}
__device__ __forceinline__ float bf16_to_f32(unsigned short h) {
    return __uint_as_float(((unsigned int)h) << 16);
}

// ---------------------------------------------------------------------------
// CSR build (both edge types at once, blockIdx.y = e), 2-level counting sort
// ---------------------------------------------------------------------------
__global__ __launch_bounds__(256) void csr_part_hist_kernel(
        const int* __restrict__ dstAll, int* __restrict__ hcoarseAll) {
    const int* dst = dstAll + (size_t)blockIdx.y * NE;
    int* hcoarse = hcoarseAll + (size_t)blockIdx.y * HCN;
    __shared__ int h[NB];
    if (threadIdx.x < NB) h[threadIdx.x] = 0;
    __syncthreads();
#pragma unroll
    for (int i = 0; i < PCH / 256; ++i) {
        int e = blockIdx.x * PCH + i * 256 + threadIdx.x;
        if (e < NE) atomicAdd(&h[dst[e] / BW], 1);
    }
    __syncthreads();
    if (threadIdx.x < NB)
        hcoarse[threadIdx.x * PB + blockIdx.x] = h[threadIdx.x];
}

__global__ __launch_bounds__(1024) void csr_scan_kernel(
        const int* __restrict__ hcoarseAll, int* __restrict__ offAll,
        int* __restrict__ bucketBaseAll, int* __restrict__ indptrAll) {
    const int* hcoarse = hcoarseAll + (size_t)blockIdx.x * HCN;
    int* off = offAll + (size_t)blockIdx.x * HCN;
    int* bucketBase = bucketBaseAll + (size_t)blockIdx.x * (NB + 1);
    int* indptr = indptrAll + (size_t)blockIdx.x * (NT + 1);
    __shared__ int ps[1024];
    int t = threadIdx.x;
    const int CH = (HCN + 1023) / 1024;  // 25
    int beg = t * CH, end = beg + CH; if (end > HCN) end = HCN;
    int s = 0;
    for (int i = beg; i < end; ++i) s += hcoarse[i];
    ps[t] = s;
    __syncthreads();
    for (int o = 1; o < 1024; o <<= 1) {
        int v = (t >= o) ? ps[t - o] : 0;
        __syncthreads();
        ps[t] += v;
        __syncthreads();
    }
    int run = (t == 0) ? 0 : ps[t - 1];
    for (int i = beg; i < end; ++i) {
        off[i] = run;
        if (i % PB == 0) bucketBase[i / PB] = run;
        run += hcoarse[i];
    }
    if (t == 1023) bucketBase[NB] = NE;
    if (t == 0) indptr[NT] = NE;
}

__global__ __launch_bounds__(256) void csr_scatter_kernel(
        const int* __restrict__ srcAll, const int* __restrict__ dstAll,
        const int* __restrict__ offAll, unsigned int* __restrict__ partAll) {
    const int* src = srcAll + (size_t)blockIdx.y * NE;
    const int* dst = dstAll + (size_t)blockIdx.y * NE;
    const int* off = offAll + (size_t)blockIdx.y * HCN;
    unsigned int* part = partAll + (size_t)blockIdx.y * NE;
    __shared__ int cur[NB];
    if (threadIdx.x < NB) cur[threadIdx.x] = off[threadIdx.x * PB + blockIdx.x];
    __syncthreads();
#pragma unroll
    for (int i = 0; i < PCH / 256; ++i) {
        int e = blockIdx.x * PCH + i * 256 + threadIdx.x;
        if (e < NE) {
            int d = dst[e];
            int b = d / BW;
            int pos = atomicAdd(&cur[b], 1);
            part[pos] = ((unsigned int)(d - b * BW) << 16) | (unsigned int)src[e];
        }
    }
}

__global__ __launch_bounds__(256) void csr_finalize_kernel(
        const unsigned int* __restrict__ partAll,
        const int* __restrict__ bucketBaseAll,
        int* __restrict__ indptrAll, int* __restrict__ esrcAll) {
    const unsigned int* part = partAll + (size_t)blockIdx.y * NE;
    const int* bucketBase = bucketBaseAll + (size_t)blockIdx.y * (NB + 1);
    int* indptr = indptrAll + (size_t)blockIdx.y * (NT + 1);
    int* esrc = esrcAll + (size_t)blockIdx.y * NE;
    __shared__ int cnt[512];
    __shared__ int excl[512];
    __shared__ int ps[256];
    __shared__ int cur[BW + 1];
    int b = blockIdx.x, t = threadIdx.x;
    int base = bucketBase[b];
    int n = bucketBase[b + 1] - base;
    cnt[t] = 0; cnt[t + 256] = 0;
    for (int j = t; j <= BW; j += 256) cur[j] = 0;
    __syncthreads();
    for (int i = t; i < n; i += 256) atomicAdd(&cnt[part[base + i] >> 16], 1);
    __syncthreads();
    int a0 = cnt[2 * t], a1 = cnt[2 * t + 1];
    ps[t] = a0 + a1;
    __syncthreads();
    for (int o = 1; o < 256; o <<= 1) {
        int v = (t >= o) ? ps[t - o] : 0;
        __syncthreads();
        ps[t] += v;
        __syncthreads();
    }
    int before = (t == 0) ? 0 : ps[t - 1];
    excl[2 * t] = before;
    excl[2 * t + 1] = before + a0;
    __syncthreads();
    int node0 = b * BW;
    for (int j = t; j < BW; j += 256) {
        int gn = node0 + j;
        if (gn < NT) indptr[gn] = base + excl[j];
    }
    for (int i = t; i < n; i += 256) {
        unsigned int pk = part[base + i];
        int dl = pk >> 16;
        int pos = atomicAdd(&cur[dl], 1);
        esrc[base + excl[dl] + pos] = (int)(pk & 0xFFFFu);
    }
}

// ---------------------------------------------------------------------------
// Aggregation + bf16 hi/lo split. One node per wave; 16-deep per half-wave:
// full chunks of 32 edges, even/odd interleave between halves (balanced at
// mean deg); one masked 32-edge tail chunk keeps depth 16 for all nodes
// (R9 lesson: never let low-degree nodes fall to shallow-MLP remainder
// loops). agg is L2-miss-service bound (FETCH=L2 miss ≈184MB mostly L3-hit);
// deeper pipelining is the remaining lever (R10: 4->8 deep gave 80->67.7us).
// ---------------------------------------------------------------------------
__global__ __launch_bounds__(256) void agg_split_kernel(
        const float* __restrict__ h, long hStride,
        const unsigned short* __restrict__ hb, long hbStride,
        const int* __restrict__ indptr2, const int* __restrict__ esrc2,
        const float* __restrict__ eps_p, int l,
        unsigned short* __restrict__ xout2) {
    int e = blockIdx.y;
    const float* hs = h + (size_t)e * hStride;
    const unsigned short* hbs = hb + (size_t)e * hbStride;
    const int* indptr = indptr2 + (size_t)e * (NT + 1);
    const int* esrc = esrc2 + (size_t)e * NE;
    unsigned short* xo = xout2 + (size_t)e * NT * 256;
    int node = blockIdx.x * 4 + (threadIdx.x >> 6);   // 1 node per wave
    if (node >= NT) return;
    int lane = threadIdx.x & 63;
    int half = lane >> 5, c = lane & 31;
    float s0 = 0.f, s1 = 0.f, s2 = 0.f, s3 = 0.f;
    if (half == 0) {
        float e1 = 1.0f + eps_p[e * 2 + l];
        float4 a = ((const float4*)hs)[(size_t)node * 32 + c];
        s0 = e1 * a.x; s1 = e1 * a.y; s2 = e1 * a.z; s3 = e1 * a.w;
    }
    int beg = indptr[node], end = indptr[node + 1];
    int deg = end - beg;
    int endFull = beg + (deg & ~31);
    int j = beg;
    for (; j < endFull; j += 32) {              // unmasked full 32-edge chunks
        int idx[16];
#pragma unroll
        for (int k = 0; k < 16; ++k) idx[k] = esrc[j + 2 * k + half];
        ushort4 v[16];
#pragma unroll
        for (int k = 0; k < 16; ++k)
            v[k] = *(const ushort4*)(hbs + (size_t)idx[k] * 128 + c * 4);
#pragma unroll
        for (int k = 0; k < 16; ++k) {
            s0 += bf16_to_f32(v[k].x);
            s1 += bf16_to_f32(v[k].y);
            s2 += bf16_to_f32(v[k].z);
            s3 += bf16_to_f32(v[k].w);
        }
    }
    if (j < end) {                              // one masked 32-edge tail
        int idx[16];
        float m[16];
#pragma unroll
        for (int k = 0; k < 16; ++k) {
            int jj = j + 2 * k + half;
            int ok = jj < end;
            idx[k] = esrc[ok ? jj : end - 1];   // clamp valid (deg > 0 here)
            m[k] = ok ? 1.f : 0.f;
        }
        ushort4 v[16];
#pragma unroll
        for (int k = 0; k < 16; ++k)
            v[k] = *(const ushort4*)(hbs + (size_t)idx[k] * 128 + c * 4);
#pragma unroll
        for (int k = 0; k < 16; ++k) {
            s0 = fmaf(bf16_to_f32(v[k].x), m[k], s0);
            s1 = fmaf(bf16_to_f32(v[k].y), m[k], s1);
            s2 = fmaf(bf16_to_f32(v[k].z), m[k], s2);
            s3 = fmaf(bf16_to_f32(v[k].w), m[k], s3);
        }
    }
    s0 += __shfl_xor(s0, 32);
    s1 += __shfl_xor(s1, 32);
    s2 += __shfl_xor(s2, 32);
    s3 += __shfl_xor(s3, 32);
    if (half == 0) {
        ushort4 hv, lv;
        hv.x = f32_to_bf16(s0); lv.x = f32_to_bf16(s0 - bf16_to_f32(hv.x));
        hv.y = f32_to_bf16(s1); lv.y = f32_to_bf16(s1 - bf16_to_f32(hv.y));
        hv.z = f32_to_bf16(s2); lv.z = f32_to_bf16(s2 - bf16_to_f32(hv.z));
        hv.w = f32_to_bf16(s3); lv.w = f32_to_bf16(s3 - bf16_to_f32(hv.w));
        *(ushort4*)(xo + (size_t)node * 256 + c * 4) = hv;
        *(ushort4*)(xo + (size_t)node * 256 + 128 + c * 4) = lv;
    }
}

// ---------------------------------------------------------------------------
// Setup mega-kernel: blocks 0..63 do weight split + frag-major repack (R4
// layout); block 0 also computes graph ranges, block 1 zeroes BN-stats,
// blocks 2..33 zero the hgp readout accumulator, blocks 64+ do feats->bf16.
// ---------------------------------------------------------------------------
__global__ __launch_bounds__(256) void setup_kernel(const float* __restrict__ Wa,
                                                    const float* __restrict__ Wb,
                                                    unsigned short* __restrict__ Bfrag,
                                                    const int* __restrict__ gid,
                                                    int* __restrict__ goff,
                                                    float* __restrict__ gsumAll,
                                                    float* __restrict__ hgp,
                                                    const float* __restrict__ feats,
                                                    unsigned short* __restrict__ featsB) {
    if (blockIdx.x >= 64) {   // tobf16: feats -> featsB (float4 granules)
        int i = (blockIdx.x - 64) * 256 + threadIdx.x;
        if (i < NT * 32) {
            float4 v = ((const float4*)feats)[i];
            ushort4 o;
            o.x = f32_to_bf16(v.x); o.y = f32_to_bf16(v.y);
            o.z = f32_to_bf16(v.z); o.w = f32_to_bf16(v.w);
            ((ushort4*)featsB)[i] = o;
        }
        return;
    }
    if (blockIdx.x == 0) {   // graph ranges
        int g = threadIdx.x;
        int lo = 0, hi = NT;
        while (lo < hi) {
            int mid = (lo + hi) >> 1;
            if (gid[mid] < g) lo = mid + 1; else hi = mid;
        }
        goff[g] = lo;
        if (g == 0) goff[NG] = NT;
    }
    if (blockIdx.x == 1) {   // zero the BN-stats accumulators (4 x 256 floats)
#pragma unroll
        for (int i = 0; i < 4; ++i) gsumAll[i * 256 + threadIdx.x] = 0.f;
    }
    if (blockIdx.x >= 2 && blockIdx.x < 34) {  // zero hgp (NG*256 floats)
        int base = (blockIdx.x - 2) * 2048 + threadIdx.x;
        hgp[base] = 0.f;
        hgp[base + 256] = 0.f;
        hgp[base + 512] = 0.f;
        hgp[base + 768] = 0.f;
        hgp[base + 1024] = 0.f;
        hgp[base + 1280] = 0.f;
        hgp[base + 1536] = 0.f;
        hgp[base + 1792] = 0.f;
    }
    int slot = blockIdx.x >> 3;
    int sub = blockIdx.x & 7;
    const float* W = (slot < 4) ? (Wa + (size_t)slot * DIM * DIM)
                                : (Wb + (size_t)(slot - 4) * DIM * DIM);
    unsigned short* out = Bfrag + (size_t)slot * 32768;
    for (int i = 0; i < 16; ++i) {
        int e = sub * 4096 + i * 256 + threadIdx.x;
        int kphys = e >> 7, n = e & 127;
        int k = kphys & 127;
        float wv = W[k * 128 + n];
        unsigned short hi = f32_to_bf16(wv);
        unsigned short val = (kphys < 128) ? hi : f32_to_bf16(wv - bf16_to_f32(hi));
        int nt = n >> 5, nin = n & 31;
        int kcp = kphys >> 4, kgp = (kphys >> 3) & 1, jj = kphys & 7;
        out[(size_t)(((nt * 16 + kcp) * 64) + kgp * 32 + nin) * 8 + jj] = val;
    }
}

// ---------------------------------------------------------------------------
// MFMA GEMM, merged encoders: blockIdx.y = e, wi = e*2 + l. ASPLIT: A from
// precomputed bf16 hi/lo rows. !ASPLIT: A fp32 + per-block BN-param calc.
// STATS: column sum/sumsq. EMITB: also write bf16 mirror of C.
// FUSERO: final layer — skip the C write and accumulate the per-graph
// readout directly from registers (sorted graph_ids -> run-flush atomics).
// ---------------------------------------------------------------------------
template <int ASPLIT, int STATS, int RELU, int EMITB, int FUSERO>
__global__ __launch_bounds__(256) void fused_gemm_kernel(
        const void* __restrict__ Asrc, long aStride,
        const unsigned short* __restrict__ BfragBase, int bOff, int l,
        const float* __restrict__ biasBase,
        const float* __restrict__ gsumBase,
        const float* __restrict__ gammaBase, const float* __restrict__ betaBase,
        float* __restrict__ C, long cStride,
        unsigned short* __restrict__ CBout, long cbStride,
        float* __restrict__ gsumOutBase,
        const int* __restrict__ gidIn, float* __restrict__ hgpOut) {
    __shared__ char smem[65536 + 1024 + 512];
    unsigned short* sB = (unsigned short*)smem;
    float* sBNa = (float*)(smem + 65536);
    float* sBNb = sBNa + 128;
    int* sgid = (int*)(smem + 65536 + 1024);
    const int ety = blockIdx.y, wi = ety * 2 + l;
    const unsigned short* Bfrag = BfragBase + (size_t)(bOff + wi) * 32768;
    const float* bias = biasBase + (size_t)wi * DIM;
    const int tid = threadIdx.x;
    const int w = tid >> 6, lane = tid & 63;
    const int nin = lane & 31, kg = lane >> 5;
    const int row0 = blockIdx.x * 128;
    const int myrow = row0 + w * 32 + nin;
    const int rowc = myrow < NT ? myrow : NT - 1;

    // stage whole B' into LDS
    {
        const uint4* Bg = (const uint4*)Bfrag;
        uint4* sB4 = (uint4*)smem;
#pragma unroll
        for (int i = 0; i < 16; ++i) sB4[tid + 256 * i] = Bg[tid + 256 * i];
    }

    s16x8 ahi[8], alo[8];
    if (ASPLIT) {
        const unsigned short* ar = (const unsigned short*)Asrc
                + (size_t)ety * aStride + (size_t)rowc * 256 + kg * 8;
#pragma unroll
        for (int kc = 0; kc < 8; ++kc) {
            ahi[kc] = *(const s16x8*)(ar + kc * 16);
            alo[kc] = *(const s16x8*)(ar + 128 + kc * 16);
        }
        __syncthreads();
    } else {
        const float* gsumIn = gsumBase + (size_t)wi * 256;
        if (tid < 128) {
            float mu = gsumIn[tid] * (1.0f / NT);
            float var = gsumIn[128 + tid] * (1.0f / NT) - mu * mu;
            float inv = rsqrtf(var + 1e-5f);
            float a = gammaBase[wi * DIM + tid] * inv;
            sBNa[tid] = a;
            sBNb[tid] = betaBase[wi * DIM + tid] - mu * a;
            if (FUSERO) {
                int rr = row0 + tid;
                sgid[tid] = gidIn[rr < NT ? rr : NT - 1];
            }
        }
        __syncthreads();   // sBN + sgid + B ready
        const float* yr = (const float*)Asrc + (size_t)ety * aStride
                + (size_t)rowc * 128 + kg * 8;
#pragma unroll
        for (int kc = 0; kc < 8; ++kc) {
            int c0 = kc * 16 + kg * 8;
            float4 y0 = *(const float4*)(yr + kc * 16);
            float4 y1 = *(const float4*)(yr + kc * 16 + 4);
            float4 a0 = *(const float4*)(sBNa + c0);
            float4 a1 = *(const float4*)(sBNa + c0 + 4);
            float4 b0 = *(const float4*)(sBNb + c0);
            float4 b1 = *(const float4*)(sBNb + c0 + 4);
            float t[8];
            t[0] = fmaxf(0.f, fmaf(y0.x, a0.x, b0.x));
            t[1] = fmaxf(0.f, fmaf(y0.y, a0.y, b0.y));
            t[2] = fmaxf(0.f, fmaf(y0.z, a0.z, b0.z));
            t[3] = fmaxf(0.f, fmaf(y0.w, a0.w, b0.w));
            t[4] = fmaxf(0.f, fmaf(y1.x, a1.x, b1.x));
            t[5] = fmaxf(0.f, fmaf(y1.y, a1.y, b1.y));
            t[6] = fmaxf(0.f, fmaf(y1.z, a1.z, b1.z));
            t[7] = fmaxf(0.f, fmaf(y1.w, a1.w, b1.w));
            union { s16x8 v; unsigned short u[8]; } H, L;
#pragma unroll
            for (int q = 0; q < 8; ++q) {
                H.u[q] = f32_to_bf16(t[q]);
                L.u[q] = f32_to_bf16(t[q] - bf16_to_f32(H.u[q]));
            }
            ahi[kc] = H.v; alo[kc] = L.v;
        }
    }

    f32x16 acc[4];
#pragma unroll
    for (int nt = 0; nt < 4; ++nt)
#pragma unroll
        for (int r = 0; r < 16; ++r) acc[nt][r] = 0.f;

#pragma unroll
    for (int nt = 0; nt < 4; ++nt) {
        const unsigned short* bp = sB + (size_t)(nt * 16) * 512 + lane * 8;
#pragma unroll
        for (int kc = 0; kc < 8; ++kc) {
            s16x8 b = *(const s16x8*)(bp + kc * 512);
            acc[nt] = __builtin_amdgcn_mfma_f32_32x32x16_bf16(ahi[kc], b, acc[nt], 0, 0, 0);
            acc[nt] = __builtin_amdgcn_mfma_f32_32x32x16_bf16(alo[kc], b, acc[nt], 0, 0, 0);
        }
#pragma unroll
        for (int kc = 0; kc < 8; ++kc) {
            s16x8 b = *(const s16x8*)(bp + (8 + kc) * 512);
            acc[nt] = __builtin_amdgcn_mfma_f32_32x32x16_bf16(ahi[kc], b, acc[nt], 0, 0, 0);
        }
    }

    if (FUSERO) {
        // readout fused: segment-sum rows into hg[g, ety*128 + col]
#pragma unroll
        for (int nt = 0; nt < 4; ++nt) {
            int col = nt * 32 + nin;
            float bv = bias[col];
            float run = 0.f;
            int curg = -1;
#pragma unroll
            for (int reg = 0; reg < 16; ++reg) {
                int lr = w * 32 + 4 * kg + (reg & 3) + 8 * (reg >> 2);
                int gr = row0 + lr;
                float v = acc[nt][reg] + bv;
                int g = sgid[lr];
                if (g != curg) {
                    if (curg >= 0)
                        atomicAdd(&hgpOut[(size_t)curg * 256 + ety * 128 + col], run);
                    curg = g;
                    run = 0.f;
                }
                run += (gr < NT) ? v : 0.f;
            }
            if (curg >= 0)
                atomicAdd(&hgpOut[(size_t)curg * 256 + ety * 128 + col], run);
        }
        return;
    }

    float* Ce = C + (size_t)ety * cStride;
    unsigned short* CBe = EMITB ? (CBout + (size_t)ety * cbStride) : nullptr;
    const int rbase = row0 + w * 32 + 4 * kg;
#pragma unroll
    for (int nt = 0; nt < 4; ++nt) {
        int col = nt * 32 + nin;
        float bv = bias[col];
#pragma unroll
        for (int reg = 0; reg < 16; ++reg) {
            int gr = rbase + (reg & 3) + 8 * (reg >> 2);
            float v = acc[nt][reg] + bv;
            if (RELU) v = fmaxf(v, 0.f);
            if (gr < NT) {
                Ce[(size_t)gr * 128 + col] = v;
                if (EMITB) CBe[(size_t)gr * 128 + col] = f32_to_bf16(v);
            }
            acc[nt][reg] = (gr < NT) ? v : 0.f;
        }
    }

    if (STATS) {
        float* gsum = gsumOutBase + (size_t)wi * 256;
        __syncthreads();
        float* ls = (float*)smem;
        ls[tid] = 0.f;
        __syncthreads();
#pragma unroll
        for (int nt = 0; nt < 4; ++nt) {
            int col = nt * 32 + nin;
            float s = 0.f, q = 0.f;
#pragma unroll
            for (int reg = 0; reg < 16; ++reg) { float v = acc[nt][reg]; s += v; q += v * v; }
            atomicAdd(&ls[col], s);
            atomicAdd(&ls[128 + col], q);
        }
        __syncthreads();
        if (tid < 128) {
            atomicAdd(&gsum[tid], ls[tid]);
            atomicAdd(&gsum[128 + tid], ls[128 + tid]);
        }
    }
}

// ---------------------------------------------------------------------------
__global__ __launch_bounds__(128) void mlp_kernel(const float* __restrict__ hgp,
                                                  const float* __restrict__ oW1,
                                                  const float* __restrict__ ob1,
                                                  const float* __restrict__ oW2,
                                                  const float* __restrict__ ob2,
                                                  const float* __restrict__ oW3,
                                                  const float* __restrict__ ob3,
                                                  float* __restrict__ out) {
    int g = blockIdx.x, t = threadIdx.x;
    __shared__ float sh[256];
    __shared__ float z[128];
    sh[t] = hgp[g * 256 + t];
    sh[t + 128] = hgp[g * 256 + 128 + t];
    __syncthreads();
    float acc = ob1[t];
    for (int k = 0; k < 256; ++k) acc = fmaf(sh[k], oW1[k * 128 + t], acc);
    float z1 = fmaxf(acc, 0.f);
    z[t] = z1;
    __syncthreads();
    acc = ob2[t];
    for (int k = 0; k < 128; ++k) acc = fmaf(z[k], oW2[k * 128 + t], acc);
    float z2 = fmaxf(acc, 0.f);
    float p = z2 * oW3[t];
    for (int off = 32; off > 0; off >>= 1) p += __shfl_down(p, off, 64);
    __shared__ float wsum[2];
    if ((t & 63) == 0) wsum[t >> 6] = p;
    __syncthreads();
    if (t == 0) out[g] = wsum[0] + wsum[1] + ob3[0];
}

// ---------------------------------------------------------------------------
extern "C" void kernel_launch(void* const* d_in, const int* in_sizes, int n_in,
                              void* d_out, int out_size, void* d_ws, size_t ws_size,
                              hipStream_t stream) {
    (void)in_sizes; (void)n_in; (void)out_size; (void)ws_size;
    const float* feats = (const float*)d_in[0];
    const int*   src   = (const int*)d_in[1];
    const int*   dst   = (const int*)d_in[2];
    const int*   gid   = (const int*)d_in[3];
    const float* epsp  = (const float*)d_in[5];
    const float* Wa    = (const float*)d_in[6];
    const float* ba    = (const float*)d_in[7];
    const float* bng   = (const float*)d_in[8];
    const float* bnb   = (const float*)d_in[9];
    const float* Wb    = (const float*)d_in[10];
    const float* bb    = (const float*)d_in[11];
    const float* oW1   = (const float*)d_in[12];
    const float* ob1   = (const float*)d_in[13];
    const float* oW2   = (const float*)d_in[14];
    const float* ob2   = (const float*)d_in[15];
    const float* oW3   = (const float*)d_in[16];
    const float* ob3   = (const float*)d_in[17];
    float* out = (float*)d_out;

    char* p = (char*)d_ws;
    auto carve = [&](size_t bytes) -> void* {
        void* r = (void*)p;
        p += (bytes + 255) & ~(size_t)255;
        return r;
    };
    unsigned short* Asplit2 = (unsigned short*)carve((size_t)2 * NT * 256 * 2);
    float* bufY2   = (float*)carve((size_t)2 * NT * DIM * 4);
    float* bufH2   = (float*)carve((size_t)2 * NT * DIM * 4);
    unsigned short* featsB = (unsigned short*)carve((size_t)NT * DIM * 2);
    unsigned short* hB2    = (unsigned short*)carve((size_t)2 * NT * DIM * 2);
    unsigned short* Bfrag  = (unsigned short*)carve((size_t)8 * 32768 * 2);
    int*   esrc2    = (int*)carve((size_t)2 * NE * 4);
    unsigned int* part2 = (unsigned int*)carve((size_t)2 * NE * 4);
    int*   hcoarse2 = (int*)carve((size_t)2 * HCN * 4);
    int*   offbuf2  = (int*)carve((size_t)2 * HCN * 4);
    int*   bb2      = (int*)carve((size_t)2 * (NB + 1) * 4);
    int*   indptr2  = (int*)carve((size_t)2 * (NT + 1) * 4);
    int*   goff     = (int*)carve((size_t)(NG + 1) * 4);
    float* gsumAll  = (float*)carve((size_t)4 * 256 * 4);  // wi x (sum|sumsq)
    float* hgp      = (float*)carve((size_t)NG * 256 * 4);

    const int CB = (NT * 32 + 255) / 256;   // tobf16 blocks

    // setup: B-split (blocks 0..63: + ranges/gsum/hgp zero) + feats->bf16
    setup_kernel<<<64 + CB, 256, 0, stream>>>(Wa, Wb, Bfrag, gid, goff,
                                              gsumAll, hgp, feats, featsB);

    // CSR for both edge types, up front
    csr_part_hist_kernel<<<dim3(PB, 2), 256, 0, stream>>>(dst, hcoarse2);
    csr_scan_kernel<<<2, 1024, 0, stream>>>(hcoarse2, offbuf2, bb2, indptr2);
    csr_scatter_kernel<<<dim3(PB, 2), 256, 0, stream>>>(src, dst, offbuf2, part2);
    csr_finalize_kernel<<<dim3(NB, 2), 256, 0, stream>>>(part2, bb2, indptr2, esrc2);

    for (int l = 0; l < 2; ++l) {
        // aggregation for both encoders in one launch
        if (l == 0)
            agg_split_kernel<<<dim3((NT + 3) / 4, 2), 256, 0, stream>>>(
                feats, 0, featsB, 0, indptr2, esrc2, epsp, l, Asplit2);
        else
            agg_split_kernel<<<dim3((NT + 3) / 4, 2), 256, 0, stream>>>(
                bufH2, (long)NT * DIM, hB2, (long)NT * DIM,
                indptr2, esrc2, epsp, l, Asplit2);
        // GEMM1 both encoders: A from Asplit, stats for BN
        fused_gemm_kernel<1, 1, 0, 0, 0><<<dim3(GEMM_B, 2), 256, 0, stream>>>(
            Asplit2, (long)NT * 256, Bfrag, 0, l, ba,
            nullptr, nullptr, nullptr,
            bufY2, (long)NT * DIM, nullptr, 0, gsumAll,
            nullptr, nullptr);
        // GEMM2 both encoders: fused BN-param + BN on A.
        //  l==0: +ReLU, write bufH + bf16 mirror (consumed by agg l=1)
        //  l==1: fused per-graph readout (no C materialization at all)
        if (l == 0)
            fused_gemm_kernel<0, 0, 1, 1, 0><<<dim3(GEMM_B, 2), 256, 0, stream>>>(
                bufY2, (long)NT * DIM, Bfrag, 4, l, bb,
                gsumAll, bng, bnb,
                bufH2, (long)NT * DIM, hB2, (long)NT * DIM, nullptr,
                nullptr, nullptr);
        else
            fused_gemm_kernel<0, 0, 0, 0, 1><<<dim3(GEMM_B, 2), 256, 0, stream>>>(
                bufY2, (long)NT * DIM, Bfrag, 4, l, bb,
                gsumAll, bng, bnb,
                nullptr, 0, nullptr, 0, nullptr,
                gid, hgp);
    }
    mlp_kernel<<<NG, 128, 0, stream>>>(hgp, oW1, ob1, oW2, ob2, oW3, ob3, out);
}

// Round 14
// 494.446 us; speedup vs baseline: 1.0815x; 1.0341x over previous
//
#include <hip/hip_runtime.h>

#define NT 50000   // nodes
#define NE 800000  // edges per edge-type
#define NG 256     // graphs
#define DIM 128
#define GEMM_B ((NT + 127) / 128)    // 391 MFMA-GEMM blocks per encoder

// CSR-build partition constants
#define NB 128                        // coarse dst buckets
#define BW 391                        // bucket width: 128*391 = 50048 >= NT
#define PB 196                        // partition blocks
#define PCH 4096                      // edges per partition block
#define HCN (NB * PB)                 // 25088

typedef short s16x8 __attribute__((ext_vector_type(8)));
typedef float f32x16 __attribute__((ext_vector_type(16)));

__device__ __forceinline__ unsigned short f32_to_bf16(float f) {
    unsigned int u = __float_as_uint(f);
    u += 0x7FFFu + ((u >> 16) & 1u);   // round-to-nearest-even
    return (unsigned short)(u >> 16);
}
__device__ __forceinline__ float bf16_to_f32(unsigned short h) {
    return __uint_as_float(((unsigned int)h) << 16);
}

// ---------------------------------------------------------------------------
// CSR build (both edge types at once, blockIdx.y = e), 2-level counting sort
// ---------------------------------------------------------------------------
__global__ __launch_bounds__(256) void csr_part_hist_kernel(
        const int* __restrict__ dstAll, int* __restrict__ hcoarseAll) {
    const int* dst = dstAll + (size_t)blockIdx.y * NE;
    int* hcoarse = hcoarseAll + (size_t)blockIdx.y * HCN;
    __shared__ int h[NB];
    if (threadIdx.x < NB) h[threadIdx.x] = 0;
    __syncthreads();
#pragma unroll
    for (int i = 0; i < PCH / 256; ++i) {
        int e = blockIdx.x * PCH + i * 256 + threadIdx.x;
        if (e < NE) atomicAdd(&h[dst[e] / BW], 1);
    }
    __syncthreads();
    if (threadIdx.x < NB)
        hcoarse[threadIdx.x * PB + blockIdx.x] = h[threadIdx.x];
}

__global__ __launch_bounds__(1024) void csr_scan_kernel(
        const int* __restrict__ hcoarseAll, int* __restrict__ offAll,
        int* __restrict__ bucketBaseAll, int* __restrict__ indptrAll) {
    const int* hcoarse = hcoarseAll + (size_t)blockIdx.x * HCN;
    int* off = offAll + (size_t)blockIdx.x * HCN;
    int* bucketBase = bucketBaseAll + (size_t)blockIdx.x * (NB + 1);
    int* indptr = indptrAll + (size_t)blockIdx.x * (NT + 1);
    __shared__ int ps[1024];
    int t = threadIdx.x;
    const int CH = (HCN + 1023) / 1024;  // 25
    int beg = t * CH, end = beg + CH; if (end > HCN) end = HCN;
    int s = 0;
    for (int i = beg; i < end; ++i) s += hcoarse[i];
    ps[t] = s;
    __syncthreads();
    for (int o = 1; o < 1024; o <<= 1) {
        int v = (t >= o) ? ps[t - o] : 0;
        __syncthreads();
        ps[t] += v;
        __syncthreads();
    }
    int run = (t == 0) ? 0 : ps[t - 1];
    for (int i = beg; i < end; ++i) {
        off[i] = run;
        if (i % PB == 0) bucketBase[i / PB] = run;
        run += hcoarse[i];
    }
    if (t == 1023) bucketBase[NB] = NE;
    if (t == 0) indptr[NT] = NE;
}

__global__ __launch_bounds__(256) void csr_scatter_kernel(
        const int* __restrict__ srcAll, const int* __restrict__ dstAll,
        const int* __restrict__ offAll, unsigned int* __restrict__ partAll) {
    const int* src = srcAll + (size_t)blockIdx.y * NE;
    const int* dst = dstAll + (size_t)blockIdx.y * NE;
    const int* off = offAll + (size_t)blockIdx.y * HCN;
    unsigned int* part = partAll + (size_t)blockIdx.y * NE;
    __shared__ int cur[NB];
    if (threadIdx.x < NB) cur[threadIdx.x] = off[threadIdx.x * PB + blockIdx.x];
    __syncthreads();
#pragma unroll
    for (int i = 0; i < PCH / 256; ++i) {
        int e = blockIdx.x * PCH + i * 256 + threadIdx.x;
        if (e < NE) {
            int d = dst[e];
            int b = d / BW;
            int pos = atomicAdd(&cur[b], 1);
            part[pos] = ((unsigned int)(d - b * BW) << 16) | (unsigned int)src[e];
        }
    }
}

__global__ __launch_bounds__(256) void csr_finalize_kernel(
        const unsigned int* __restrict__ partAll,
        const int* __restrict__ bucketBaseAll,
        int* __restrict__ indptrAll, int* __restrict__ esrcAll) {
    const unsigned int* part = partAll + (size_t)blockIdx.y * NE;
    const int* bucketBase = bucketBaseAll + (size_t)blockIdx.y * (NB + 1);
    int* indptr = indptrAll + (size_t)blockIdx.y * (NT + 1);
    int* esrc = esrcAll + (size_t)blockIdx.y * NE;
    __shared__ int cnt[512];
    __shared__ int excl[512];
    __shared__ int ps[256];
    __shared__ int cur[BW + 1];
    int b = blockIdx.x, t = threadIdx.x;
    int base = bucketBase[b];
    int n = bucketBase[b + 1] - base;
    cnt[t] = 0; cnt[t + 256] = 0;
    for (int j = t; j <= BW; j += 256) cur[j] = 0;
    __syncthreads();
    for (int i = t; i < n; i += 256) atomicAdd(&cnt[part[base + i] >> 16], 1);
    __syncthreads();
    int a0 = cnt[2 * t], a1 = cnt[2 * t + 1];
    ps[t] = a0 + a1;
    __syncthreads();
    for (int o = 1; o < 256; o <<= 1) {
        int v = (t >= o) ? ps[t - o] : 0;
        __syncthreads();
        ps[t] += v;
        __syncthreads();
    }
    int before = (t == 0) ? 0 : ps[t - 1];
    excl[2 * t] = before;
    excl[2 * t + 1] = before + a0;
    __syncthreads();
    int node0 = b * BW;
    for (int j = t; j < BW; j += 256) {
        int gn = node0 + j;
        if (gn < NT) indptr[gn] = base + excl[j];
    }
    for (int i = t; i < n; i += 256) {
        unsigned int pk = part[base + i];
        int dl = pk >> 16;
        int pos = atomicAdd(&cur[dl], 1);
        esrc[base + excl[dl] + pos] = (int)(pk & 0xFFFFu);
    }
}

// ---------------------------------------------------------------------------
// Aggregation + bf16 hi/lo split — R12 configuration (best measured: 67 µs,
// VGPR 28, occupancy 71%). One node per wave; half-wave hw owns edges
// [j+8hw, j+8hw+8) of each 16-edge chunk; full chunks unmasked, one masked
// 8-deep tail chunk. R13 lesson: 16-deep costs occupancy (VGPR 40) and
// doubles wasted clamped loads at mean deg 16 — depth 8 is the knee.
// ---------------------------------------------------------------------------
__global__ __launch_bounds__(256) void agg_split_kernel(
        const float* __restrict__ h, long hStride,
        const unsigned short* __restrict__ hb, long hbStride,
        const int* __restrict__ indptr2, const int* __restrict__ esrc2,
        const float* __restrict__ eps_p, int l,
        unsigned short* __restrict__ xout2) {
    int e = blockIdx.y;
    const float* hs = h + (size_t)e * hStride;
    const unsigned short* hbs = hb + (size_t)e * hbStride;
    const int* indptr = indptr2 + (size_t)e * (NT + 1);
    const int* esrc = esrc2 + (size_t)e * NE;
    unsigned short* xo = xout2 + (size_t)e * NT * 256;
    int node = blockIdx.x * 4 + (threadIdx.x >> 6);   // 1 node per wave
    if (node >= NT) return;
    int lane = threadIdx.x & 63;
    int half = lane >> 5, c = lane & 31;
    float s0 = 0.f, s1 = 0.f, s2 = 0.f, s3 = 0.f;
    if (half == 0) {
        float e1 = 1.0f + eps_p[e * 2 + l];
        float4 a = ((const float4*)hs)[(size_t)node * 32 + c];
        s0 = e1 * a.x; s1 = e1 * a.y; s2 = e1 * a.z; s3 = e1 * a.w;
    }
    int beg = indptr[node], end = indptr[node + 1];
    int deg = end - beg;
    int endFull = beg + (deg & ~15);
    int j = beg;
    for (; j < endFull; j += 16) {              // unmasked full chunks
        int b0 = j + half * 8;
        int idx[8];
#pragma unroll
        for (int k = 0; k < 8; ++k) idx[k] = esrc[b0 + k];
        ushort4 v[8];
#pragma unroll
        for (int k = 0; k < 8; ++k)
            v[k] = *(const ushort4*)(hbs + (size_t)idx[k] * 128 + c * 4);
#pragma unroll
        for (int k = 0; k < 8; ++k) {
            s0 += bf16_to_f32(v[k].x);
            s1 += bf16_to_f32(v[k].y);
            s2 += bf16_to_f32(v[k].z);
            s3 += bf16_to_f32(v[k].w);
        }
    }
    if (j < end) {                              // one masked 8-deep tail chunk
        int b0 = j + half * 8;
        int idx[8];
        float m[8];
#pragma unroll
        for (int k = 0; k < 8; ++k) {
            int jj = b0 + k;
            int ok = jj < end;
            idx[k] = esrc[ok ? jj : end - 1];   // clamp valid (deg > 0 here)
            m[k] = ok ? 1.f : 0.f;
        }
        ushort4 v[8];
#pragma unroll
        for (int k = 0; k < 8; ++k)
            v[k] = *(const ushort4*)(hbs + (size_t)idx[k] * 128 + c * 4);
#pragma unroll
        for (int k = 0; k < 8; ++k) {
            s0 = fmaf(bf16_to_f32(v[k].x), m[k], s0);
            s1 = fmaf(bf16_to_f32(v[k].y), m[k], s1);
            s2 = fmaf(bf16_to_f32(v[k].z), m[k], s2);
            s3 = fmaf(bf16_to_f32(v[k].w), m[k], s3);
        }
    }
    s0 += __shfl_xor(s0, 32);
    s1 += __shfl_xor(s1, 32);
    s2 += __shfl_xor(s2, 32);
    s3 += __shfl_xor(s3, 32);
    if (half == 0) {
        ushort4 hv, lv;
        hv.x = f32_to_bf16(s0); lv.x = f32_to_bf16(s0 - bf16_to_f32(hv.x));
        hv.y = f32_to_bf16(s1); lv.y = f32_to_bf16(s1 - bf16_to_f32(hv.y));
        hv.z = f32_to_bf16(s2); lv.z = f32_to_bf16(s2 - bf16_to_f32(hv.z));
        hv.w = f32_to_bf16(s3); lv.w = f32_to_bf16(s3 - bf16_to_f32(hv.w));
        *(ushort4*)(xo + (size_t)node * 256 + c * 4) = hv;
        *(ushort4*)(xo + (size_t)node * 256 + 128 + c * 4) = lv;
    }
}

// ---------------------------------------------------------------------------
// Setup mega-kernel: blocks 0..63 do weight split + frag-major repack (R4
// layout); block 0 also computes graph ranges, block 1 zeroes BN-stats,
// blocks 2..33 zero the hgp readout accumulator, blocks 64+ do feats->bf16.
// (R13: this fusion saved ~25 µs of launch overhead — keep.)
// ---------------------------------------------------------------------------
__global__ __launch_bounds__(256) void setup_kernel(const float* __restrict__ Wa,
                                                    const float* __restrict__ Wb,
                                                    unsigned short* __restrict__ Bfrag,
                                                    const int* __restrict__ gid,
                                                    int* __restrict__ goff,
                                                    float* __restrict__ gsumAll,
                                                    float* __restrict__ hgp,
                                                    const float* __restrict__ feats,
                                                    unsigned short* __restrict__ featsB) {
    if (blockIdx.x >= 64) {   // tobf16: feats -> featsB (float4 granules)
        int i = (blockIdx.x - 64) * 256 + threadIdx.x;
        if (i < NT * 32) {
            float4 v = ((const float4*)feats)[i];
            ushort4 o;
            o.x = f32_to_bf16(v.x); o.y = f32_to_bf16(v.y);
            o.z = f32_to_bf16(v.z); o.w = f32_to_bf16(v.w);
            ((ushort4*)featsB)[i] = o;
        }
        return;
    }
    if (blockIdx.x == 0) {   // graph ranges
        int g = threadIdx.x;
        int lo = 0, hi = NT;
        while (lo < hi) {
            int mid = (lo + hi) >> 1;
            if (gid[mid] < g) lo = mid + 1; else hi = mid;
        }
        goff[g] = lo;
        if (g == 0) goff[NG] = NT;
    }
    if (blockIdx.x == 1) {   // zero the BN-stats accumulators (4 x 256 floats)
#pragma unroll
        for (int i = 0; i < 4; ++i) gsumAll[i * 256 + threadIdx.x] = 0.f;
    }
    if (blockIdx.x >= 2 && blockIdx.x < 34) {  // zero hgp (NG*256 floats)
        int base = (blockIdx.x - 2) * 2048 + threadIdx.x;
        hgp[base] = 0.f;
        hgp[base + 256] = 0.f;
        hgp[base + 512] = 0.f;
        hgp[base + 768] = 0.f;
        hgp[base + 1024] = 0.f;
        hgp[base + 1280] = 0.f;
        hgp[base + 1536] = 0.f;
        hgp[base + 1792] = 0.f;
    }
    int slot = blockIdx.x >> 3;
    int sub = blockIdx.x & 7;
    const float* W = (slot < 4) ? (Wa + (size_t)slot * DIM * DIM)
                                : (Wb + (size_t)(slot - 4) * DIM * DIM);
    unsigned short* out = Bfrag + (size_t)slot * 32768;
    for (int i = 0; i < 16; ++i) {
        int e = sub * 4096 + i * 256 + threadIdx.x;
        int kphys = e >> 7, n = e & 127;
        int k = kphys & 127;
        float wv = W[k * 128 + n];
        unsigned short hi = f32_to_bf16(wv);
        unsigned short val = (kphys < 128) ? hi : f32_to_bf16(wv - bf16_to_f32(hi));
        int nt = n >> 5, nin = n & 31;
        int kcp = kphys >> 4, kgp = (kphys >> 3) & 1, jj = kphys & 7;
        out[(size_t)(((nt * 16 + kcp) * 64) + kgp * 32 + nin) * 8 + jj] = val;
    }
}

// ---------------------------------------------------------------------------
// MFMA GEMM, merged encoders: blockIdx.y = e, wi = e*2 + l. ASPLIT: A from
// precomputed bf16 hi/lo rows. !ASPLIT: A fp32 + per-block BN-param calc.
// STATS: column sum/sumsq. EMITB: also write bf16 mirror of C.
// FUSERO: final layer — skip the C write and accumulate the per-graph
// readout directly from registers (sorted graph_ids -> run-flush atomics).
// ---------------------------------------------------------------------------
template <int ASPLIT, int STATS, int RELU, int EMITB, int FUSERO>
__global__ __launch_bounds__(256) void fused_gemm_kernel(
        const void* __restrict__ Asrc, long aStride,
        const unsigned short* __restrict__ BfragBase, int bOff, int l,
        const float* __restrict__ biasBase,
        const float* __restrict__ gsumBase,
        const float* __restrict__ gammaBase, const float* __restrict__ betaBase,
        float* __restrict__ C, long cStride,
        unsigned short* __restrict__ CBout, long cbStride,
        float* __restrict__ gsumOutBase,
        const int* __restrict__ gidIn, float* __restrict__ hgpOut) {
    __shared__ char smem[65536 + 1024 + 512];
    unsigned short* sB = (unsigned short*)smem;
    float* sBNa = (float*)(smem + 65536);
    float* sBNb = sBNa + 128;
    int* sgid = (int*)(smem + 65536 + 1024);
    const int ety = blockIdx.y, wi = ety * 2 + l;
    const unsigned short* Bfrag = BfragBase + (size_t)(bOff + wi) * 32768;
    const float* bias = biasBase + (size_t)wi * DIM;
    const int tid = threadIdx.x;
    const int w = tid >> 6, lane = tid & 63;
    const int nin = lane & 31, kg = lane >> 5;
    const int row0 = blockIdx.x * 128;
    const int myrow = row0 + w * 32 + nin;
    const int rowc = myrow < NT ? myrow : NT - 1;

    // stage whole B' into LDS
    {
        const uint4* Bg = (const uint4*)Bfrag;
        uint4* sB4 = (uint4*)smem;
#pragma unroll
        for (int i = 0; i < 16; ++i) sB4[tid + 256 * i] = Bg[tid + 256 * i];
    }

    s16x8 ahi[8], alo[8];
    if (ASPLIT) {
        const unsigned short* ar = (const unsigned short*)Asrc
                + (size_t)ety * aStride + (size_t)rowc * 256 + kg * 8;
#pragma unroll
        for (int kc = 0; kc < 8; ++kc) {
            ahi[kc] = *(const s16x8*)(ar + kc * 16);
            alo[kc] = *(const s16x8*)(ar + 128 + kc * 16);
        }
        __syncthreads();
    } else {
        const float* gsumIn = gsumBase + (size_t)wi * 256;
        if (tid < 128) {
            float mu = gsumIn[tid] * (1.0f / NT);
            float var = gsumIn[128 + tid] * (1.0f / NT) - mu * mu;
            float inv = rsqrtf(var + 1e-5f);
            float a = gammaBase[wi * DIM + tid] * inv;
            sBNa[tid] = a;
            sBNb[tid] = betaBase[wi * DIM + tid] - mu * a;
            if (FUSERO) {
                int rr = row0 + tid;
                sgid[tid] = gidIn[rr < NT ? rr : NT - 1];
            }
        }
        __syncthreads();   // sBN + sgid + B ready
        const float* yr = (const float*)Asrc + (size_t)ety * aStride
                + (size_t)rowc * 128 + kg * 8;
#pragma unroll
        for (int kc = 0; kc < 8; ++kc) {
            int c0 = kc * 16 + kg * 8;
            float4 y0 = *(const float4*)(yr + kc * 16);
            float4 y1 = *(const float4*)(yr + kc * 16 + 4);
            float4 a0 = *(const float4*)(sBNa + c0);
            float4 a1 = *(const float4*)(sBNa + c0 + 4);
            float4 b0 = *(const float4*)(sBNb + c0);
            float4 b1 = *(const float4*)(sBNb + c0 + 4);
            float t[8];
            t[0] = fmaxf(0.f, fmaf(y0.x, a0.x, b0.x));
            t[1] = fmaxf(0.f, fmaf(y0.y, a0.y, b0.y));
            t[2] = fmaxf(0.f, fmaf(y0.z, a0.z, b0.z));
            t[3] = fmaxf(0.f, fmaf(y0.w, a0.w, b0.w));
            t[4] = fmaxf(0.f, fmaf(y1.x, a1.x, b1.x));
            t[5] = fmaxf(0.f, fmaf(y1.y, a1.y, b1.y));
            t[6] = fmaxf(0.f, fmaf(y1.z, a1.z, b1.z));
            t[7] = fmaxf(0.f, fmaf(y1.w, a1.w, b1.w));
            union { s16x8 v; unsigned short u[8]; } H, L;
#pragma unroll
            for (int q = 0; q < 8; ++q) {
                H.u[q] = f32_to_bf16(t[q]);
                L.u[q] = f32_to_bf16(t[q] - bf16_to_f32(H.u[q]));
            }
            ahi[kc] = H.v; alo[kc] = L.v;
        }
    }

    f32x16 acc[4];
#pragma unroll
    for (int nt = 0; nt < 4; ++nt)
#pragma unroll
        for (int r = 0; r < 16; ++r) acc[nt][r] = 0.f;

#pragma unroll
    for (int nt = 0; nt < 4; ++nt) {
        const unsigned short* bp = sB + (size_t)(nt * 16) * 512 + lane * 8;
#pragma unroll
        for (int kc = 0; kc < 8; ++kc) {
            s16x8 b = *(const s16x8*)(bp + kc * 512);
            acc[nt] = __builtin_amdgcn_mfma_f32_32x32x16_bf16(ahi[kc], b, acc[nt], 0, 0, 0);
            acc[nt] = __builtin_amdgcn_mfma_f32_32x32x16_bf16(alo[kc], b, acc[nt], 0, 0, 0);
        }
#pragma unroll
        for (int kc = 0; kc < 8; ++kc) {
            s16x8 b = *(const s16x8*)(bp + (8 + kc) * 512);
            acc[nt] = __builtin_amdgcn_mfma_f32_32x32x16_bf16(ahi[kc], b, acc[nt], 0, 0, 0);
        }
    }

    if (FUSERO) {
        // readout fused: segment-sum rows into hg[g, ety*128 + col]
#pragma unroll
        for (int nt = 0; nt < 4; ++nt) {
            int col = nt * 32 + nin;
            float bv = bias[col];
            float run = 0.f;
            int curg = -1;
#pragma unroll
            for (int reg = 0; reg < 16; ++reg) {
                int lr = w * 32 + 4 * kg + (reg & 3) + 8 * (reg >> 2);
                int gr = row0 + lr;
                float v = acc[nt][reg] + bv;
                int g = sgid[lr];
                if (g != curg) {
                    if (curg >= 0)
                        atomicAdd(&hgpOut[(size_t)curg * 256 + ety * 128 + col], run);
                    curg = g;
                    run = 0.f;
                }
                run += (gr < NT) ? v : 0.f;
            }
            if (curg >= 0)
                atomicAdd(&hgpOut[(size_t)curg * 256 + ety * 128 + col], run);
        }
        return;
    }

    float* Ce = C + (size_t)ety * cStride;
    unsigned short* CBe = EMITB ? (CBout + (size_t)ety * cbStride) : nullptr;
    const int rbase = row0 + w * 32 + 4 * kg;
#pragma unroll
    for (int nt = 0; nt < 4; ++nt) {
        int col = nt * 32 + nin;
        float bv = bias[col];
#pragma unroll
        for (int reg = 0; reg < 16; ++reg) {
            int gr = rbase + (reg & 3) + 8 * (reg >> 2);
            float v = acc[nt][reg] + bv;
            if (RELU) v = fmaxf(v, 0.f);
            if (gr < NT) {
                Ce[(size_t)gr * 128 + col] = v;
                if (EMITB) CBe[(size_t)gr * 128 + col] = f32_to_bf16(v);
            }
            acc[nt][reg] = (gr < NT) ? v : 0.f;
        }
    }

    if (STATS) {
        float* gsum = gsumOutBase + (size_t)wi * 256;
        __syncthreads();
        float* ls = (float*)smem;
        ls[tid] = 0.f;
        __syncthreads();
#pragma unroll
        for (int nt = 0; nt < 4; ++nt) {
            int col = nt * 32 + nin;
            float s = 0.f, q = 0.f;
#pragma unroll
            for (int reg = 0; reg < 16; ++reg) { float v = acc[nt][reg]; s += v; q += v * v; }
            atomicAdd(&ls[col], s);
            atomicAdd(&ls[128 + col], q);
        }
        __syncthreads();
        if (tid < 128) {
            atomicAdd(&gsum[tid], ls[tid]);
            atomicAdd(&gsum[128 + tid], ls[128 + tid]);
        }
    }
}

// ---------------------------------------------------------------------------
__global__ __launch_bounds__(128) void mlp_kernel(const float* __restrict__ hgp,
                                                  const float* __restrict__ oW1,
                                                  const float* __restrict__ ob1,
                                                  const float* __restrict__ oW2,
                                                  const float* __restrict__ ob2,
                                                  const float* __restrict__ oW3,
                                                  const float* __restrict__ ob3,
                                                  float* __restrict__ out) {
    int g = blockIdx.x, t = threadIdx.x;
    __shared__ float sh[256];
    __shared__ float z[128];
    sh[t] = hgp[g * 256 + t];
    sh[t + 128] = hgp[g * 256 + 128 + t];
    __syncthreads();
    float acc = ob1[t];
    for (int k = 0; k < 256; ++k) acc = fmaf(sh[k], oW1[k * 128 + t], acc);
    float z1 = fmaxf(acc, 0.f);
    z[t] = z1;
    __syncthreads();
    acc = ob2[t];
    for (int k = 0; k < 128; ++k) acc = fmaf(z[k], oW2[k * 128 + t], acc);
    float z2 = fmaxf(acc, 0.f);
    float p = z2 * oW3[t];
    for (int off = 32; off > 0; off >>= 1) p += __shfl_down(p, off, 64);
    __shared__ float wsum[2];
    if ((t & 63) == 0) wsum[t >> 6] = p;
    __syncthreads();
    if (t == 0) out[g] = wsum[0] + wsum[1] + ob3[0];
}

// ---------------------------------------------------------------------------
extern "C" void kernel_launch(void* const* d_in, const int* in_sizes, int n_in,
                              void* d_out, int out_size, void* d_ws, size_t ws_size,
                              hipStream_t stream) {
    (void)in_sizes; (void)n_in; (void)out_size; (void)ws_size;
    const float* feats = (const float*)d_in[0];
    const int*   src   = (const int*)d_in[1];
    const int*   dst   = (const int*)d_in[2];
    const int*   gid   = (const int*)d_in[3];
    const float* epsp  = (const float*)d_in[5];
    const float* Wa    = (const float*)d_in[6];
    const float* ba    = (const float*)d_in[7];
    const float* bng   = (const float*)d_in[8];
    const float* bnb   = (const float*)d_in[9];
    const float* Wb    = (const float*)d_in[10];
    const float* bb    = (const float*)d_in[11];
    const float* oW1   = (const float*)d_in[12];
    const float* ob1   = (const float*)d_in[13];
    const float* oW2   = (const float*)d_in[14];
    const float* ob2   = (const float*)d_in[15];
    const float* oW3   = (const float*)d_in[16];
    const float* ob3   = (const float*)d_in[17];
    float* out = (float*)d_out;

    char* p = (char*)d_ws;
    auto carve = [&](size_t bytes) -> void* {
        void* r = (void*)p;
        p += (bytes + 255) & ~(size_t)255;
        return r;
    };
    unsigned short* Asplit2 = (unsigned short*)carve((size_t)2 * NT * 256 * 2);
    float* bufY2   = (float*)carve((size_t)2 * NT * DIM * 4);
    float* bufH2   = (float*)carve((size_t)2 * NT * DIM * 4);
    unsigned short* featsB = (unsigned short*)carve((size_t)NT * DIM * 2);
    unsigned short* hB2    = (unsigned short*)carve((size_t)2 * NT * DIM * 2);
    unsigned short* Bfrag  = (unsigned short*)carve((size_t)8 * 32768 * 2);
    int*   esrc2    = (int*)carve((size_t)2 * NE * 4);
    unsigned int* part2 = (unsigned int*)carve((size_t)2 * NE * 4);
    int*   hcoarse2 = (int*)carve((size_t)2 * HCN * 4);
    int*   offbuf2  = (int*)carve((size_t)2 * HCN * 4);
    int*   bb2      = (int*)carve((size_t)2 * (NB + 1) * 4);
    int*   indptr2  = (int*)carve((size_t)2 * (NT + 1) * 4);
    int*   goff     = (int*)carve((size_t)(NG + 1) * 4);
    float* gsumAll  = (float*)carve((size_t)4 * 256 * 4);  // wi x (sum|sumsq)
    float* hgp      = (float*)carve((size_t)NG * 256 * 4);

    const int CB = (NT * 32 + 255) / 256;   // tobf16 blocks

    // setup: B-split (blocks 0..63: + ranges/gsum/hgp zero) + feats->bf16
    setup_kernel<<<64 + CB, 256, 0, stream>>>(Wa, Wb, Bfrag, gid, goff,
                                              gsumAll, hgp, feats, featsB);

    // CSR for both edge types, up front
    csr_part_hist_kernel<<<dim3(PB, 2), 256, 0, stream>>>(dst, hcoarse2);
    csr_scan_kernel<<<2, 1024, 0, stream>>>(hcoarse2, offbuf2, bb2, indptr2);
    csr_scatter_kernel<<<dim3(PB, 2), 256, 0, stream>>>(src, dst, offbuf2, part2);
    csr_finalize_kernel<<<dim3(NB, 2), 256, 0, stream>>>(part2, bb2, indptr2, esrc2);

    for (int l = 0; l < 2; ++l) {
        // aggregation for both encoders in one launch
        if (l == 0)
            agg_split_kernel<<<dim3((NT + 3) / 4, 2), 256, 0, stream>>>(
                feats, 0, featsB, 0, indptr2, esrc2, epsp, l, Asplit2);
        else
            agg_split_kernel<<<dim3((NT + 3) / 4, 2), 256, 0, stream>>>(
                bufH2, (long)NT * DIM, hB2, (long)NT * DIM,
                indptr2, esrc2, epsp, l, Asplit2);
        // GEMM1 both encoders: A from Asplit, stats for BN
        fused_gemm_kernel<1, 1, 0, 0, 0><<<dim3(GEMM_B, 2), 256, 0, stream>>>(
            Asplit2, (long)NT * 256, Bfrag, 0, l, ba,
            nullptr, nullptr, nullptr,
            bufY2, (long)NT * DIM, nullptr, 0, gsumAll,
            nullptr, nullptr);
        // GEMM2 both encoders: fused BN-param + BN on A.
        //  l==0: +ReLU, write bufH + bf16 mirror (consumed by agg l=1)
        //  l==1: fused per-graph readout (no C materialization at all)
        if (l == 0)
            fused_gemm_kernel<0, 0, 1, 1, 0><<<dim3(GEMM_B, 2), 256, 0, stream>>>(
                bufY2, (long)NT * DIM, Bfrag, 4, l, bb,
                gsumAll, bng, bnb,
                bufH2, (long)NT * DIM, hB2, (long)NT * DIM, nullptr,
                nullptr, nullptr);
        else
            fused_gemm_kernel<0, 0, 0, 0, 1><<<dim3(GEMM_B, 2), 256, 0, stream>>>(
                bufY2, (long)NT * DIM, Bfrag, 4, l, bb,
                gsumAll, bng, bnb,
                nullptr, 0, nullptr, 0, nullptr,
                gid, hgp);
    }
    mlp_kernel<<<NG, 128, 0, stream>>>(hgp, oW1, ob1, oW2, ob2, oW3, ob3, out);
}